// Round 5
// baseline (1843.716 us; speedup 1.0000x reference)
//
#include <hip/hip_runtime.h>
#include <cstddef>
#include <cmath>
#include <utility>

#define B_ 16
#define LQ_ 300
#define D_ 256
#define NH_ 8
#define HD_ 32
#define FF_ 1024
#define NBIN_ 33
#define NC_ 80
#define SUMP_ 12
#define STOT_ 8400
#define R_ (B_*LQ_)        // 4800
#define NLAYERS_ 6

typedef short bf16x8 __attribute__((ext_vector_type(8)));
typedef float f32x4  __attribute__((ext_vector_type(4)));

static __device__ __forceinline__ short f2bf(float x) {
  union { float f; unsigned u; } v; v.f = x;
  unsigned r = v.u + 0x7fffu + ((v.u >> 16) & 1u);   // RNE
  return (short)(r >> 16);
}
static __device__ __forceinline__ float bf2f(short s) {
  union { unsigned u; float f; } v; v.u = ((unsigned)(unsigned short)s) << 16; return v.f;
}

// ---------------------------------------------------------------------------
// One-dispatch weight convert+transpose for ALL weights.
// ---------------------------------------------------------------------------
struct WJob { const float* src; short* dst; int K, N, tk, tn, L, ostride, blk0, pad; };
struct WJobs { WJob j[17]; int njobs; };

__launch_bounds__(256)
__global__ void wconv_all(WJobs P) {
  __shared__ float t[32][33];
  const int b = blockIdx.x;
  int ji = 0;
  for (int k = 1; k < P.njobs; ++k) ji = (b >= P.j[k].blk0) ? k : ji;
  const float* src = P.j[ji].src;
  short* dst = P.j[ji].dst;
  const int K = P.j[ji].K, N = P.j[ji].N, tk = P.j[ji].tk;
  int rel = b - P.j[ji].blk0;
  int per = tk * P.j[ji].tn;
  int l = rel / per; int r2 = rel - l * per;
  int tki = r2 % tk, tni = r2 / tk;
  const float* Wl = src + (size_t)l * K * N;
  short* Wtl = dst + (size_t)l * (size_t)P.j[ji].ostride;
  int k0 = tki * 32, n0 = tni * 32;
  int tr = threadIdx.x >> 5, tc = threadIdx.x & 31;
  #pragma unroll
  for (int i = 0; i < 4; ++i) {
    int k = k0 + tr + i * 8, n = n0 + tc;
    t[tr + i * 8][tc] = (k < K && n < N) ? Wl[(size_t)k * N + n] : 0.f;
  }
  __syncthreads();
  #pragma unroll
  for (int i = 0; i < 4; ++i) {
    int n = n0 + tr + i * 8, k = k0 + tc;
    if (n < N && k < K) Wtl[(size_t)n * K + k] = f2bf(t[tc][tr + i * 8]);
  }
}

// memory fp32 [B,S,256] -> bf16 head-major [B,NH,S,32]
__launch_bounds__(256)
__global__ void memconv_kernel(const float* __restrict__ mem, short* __restrict__ mb) {
  int gs = blockIdx.x * 4 + (threadIdx.x >> 6);
  int c  = (threadIdx.x & 63) * 4;
  int b = gs / STOT_, s = gs - b * STOT_;
  float4 v = *(const float4*)(mem + (size_t)gs * 256 + c);
  int h = c >> 5, cc = c & 31;
  short4 o; o.x = f2bf(v.x); o.y = f2bf(v.y); o.z = f2bf(v.z); o.w = f2bf(v.w);
  *(short4*)(mb + (((size_t)(b * 8 + h) * STOT_ + s) * 32) + cc) = o;
}

// ---------------------------------------------------------------------------
// One-dispatch init.
// ---------------------------------------------------------------------------
__launch_bounds__(256)
__global__ void misc_init(const float* __restrict__ target, const float* __restrict__ refu,
                          const float* __restrict__ qb, const float* __restrict__ kb,
                          const float* __restrict__ vb, const float* __restrict__ ob,
                          const float* __restrict__ ab,
                          float* __restrict__ output, short* __restrict__ outbf,
                          float* __restrict__ out_prev, float* __restrict__ cprev,
                          float* __restrict__ refcur, float* __restrict__ qkvb,
                          float* __restrict__ offawb) {
  int i = blockIdx.x * 256 + threadIdx.x;
  float4 z; z.x = 0.f; z.y = 0.f; z.z = 0.f; z.w = 0.f;
  if (i < R_ * 64) {
    float4 v = ((const float4*)target)[i];
    ((float4*)output)[i] = v;
    short4 s; s.x = f2bf(v.x); s.y = f2bf(v.y); s.z = f2bf(v.z); s.w = f2bf(v.w);
    ((short4*)outbf)[i] = s;
    ((float4*)out_prev)[i] = z;
  }
  if (i < R_ * 33) ((float4*)cprev)[i] = z;
  if (i < R_) {
    float4 r = ((const float4*)refu)[i];
    float4 o;
    o.x = 1.f / (1.f + __expf(-r.x)); o.y = 1.f / (1.f + __expf(-r.y));
    o.z = 1.f / (1.f + __expf(-r.z)); o.w = 1.f / (1.f + __expf(-r.w));
    ((float4*)refcur)[i] = o;
  }
  if (i < NLAYERS_ * 768) {
    int l = i / 768, c = i % 768;
    qkvb[i] = (c < 256) ? qb[l * 256 + c] : (c < 512) ? kb[l * 256 + c - 256]
                        : vb[l * 256 + c - 512];
  }
  if (i < NLAYERS_ * 288) {
    int l = i / 288, c = i % 288;
    offawb[i] = (c < 192) ? ob[l * 192 + c] : ab[l * 96 + c - 192];
  }
}

// ---------------------------------------------------------------------------
// Standalone qp MLP + qkv GEMM (layer 0 only). 32 rows x 8 waves, grid 150.
// ---------------------------------------------------------------------------
__launch_bounds__(512)
__global__ void qp_qkv(const float* __restrict__ ref, const float* __restrict__ W1,
                       const float* __restrict__ b1, const short* __restrict__ W2t,
                       const float* __restrict__ b2, const float* __restrict__ output,
                       const short* __restrict__ outbf,
                       const short* __restrict__ Qt, const float* __restrict__ qkvbias,
                       float* __restrict__ qpout, short* __restrict__ qkvout) {
  __shared__ short sh[32 * 520];
  __shared__ short oqs[32][264];
  const int m0 = blockIdx.x * 32;
  const int tid = threadIdx.x;
  for (int i = tid; i < 32 * 512; i += 512) {
    int r = i >> 9, n = i & 511;
    float4 rv = *(const float4*)(ref + (size_t)(m0 + r) * 4);
    float v = b1[n] + rv.x * W1[n] + rv.y * W1[512 + n] + rv.z * W1[1024 + n]
            + rv.w * W1[1536 + n];
    v = v / (1.f + __expf(-v));
    sh[r * 520 + n] = f2bf(v);
  }
  __syncthreads();
  const int wid = tid >> 6, lane = tid & 63;
  const int lr = lane & 15, lq = lane >> 4;
  {
    f32x4 acc[2][2];
    #pragma unroll
    for (int ti = 0; ti < 2; ++ti)
      #pragma unroll
      for (int t = 0; t < 2; ++t) acc[ti][t] = (f32x4){0.f, 0.f, 0.f, 0.f};
    #pragma unroll 4
    for (int k0 = 0; k0 < 512; k0 += 32) {
      bf16x8 a0 = *(const bf16x8*)&sh[lr * 520 + k0 + lq * 8];
      bf16x8 a1 = *(const bf16x8*)&sh[(16 + lr) * 520 + k0 + lq * 8];
      #pragma unroll
      for (int t = 0; t < 2; ++t) {
        bf16x8 w = *(const bf16x8*)(W2t + (size_t)(wid * 32 + t * 16 + lr) * 512 + k0 + lq * 8);
        acc[0][t] = __builtin_amdgcn_mfma_f32_16x16x32_bf16(a0, w, acc[0][t], 0, 0, 0);
        acc[1][t] = __builtin_amdgcn_mfma_f32_16x16x32_bf16(a1, w, acc[1][t], 0, 0, 0);
      }
    }
    #pragma unroll
    for (int t = 0; t < 2; ++t) {
      int col = wid * 32 + t * 16 + lr;
      float bv = b2[col];
      #pragma unroll
      for (int ti = 0; ti < 2; ++ti)
        #pragma unroll
        for (int rr = 0; rr < 4; ++rr) {
          int rl = ti * 16 + lq * 4 + rr;
          size_t idx = (size_t)(m0 + rl) * 256 + col;
          float v = fminf(fmaxf(acc[ti][t][rr] + bv, -10.f), 10.f);
          qpout[idx] = v;
          oqs[rl][col] = f2bf(v + output[idx]);
        }
    }
  }
  __syncthreads();
  {
    f32x4 acc[2][6];
    #pragma unroll
    for (int ti = 0; ti < 2; ++ti)
      #pragma unroll
      for (int t = 0; t < 6; ++t) acc[ti][t] = (f32x4){0.f, 0.f, 0.f, 0.f};
    const int cbase = wid * 96;
    const short* obp0 = outbf + (size_t)(m0 + lr) * 256;
    const short* obp1 = outbf + (size_t)(m0 + 16 + lr) * 256;
    #pragma unroll 2
    for (int k0 = 0; k0 < 256; k0 += 32) {
      bf16x8 aq0 = *(const bf16x8*)&oqs[lr][k0 + lq * 8];
      bf16x8 aq1 = *(const bf16x8*)&oqs[16 + lr][k0 + lq * 8];
      bf16x8 ab0 = *(const bf16x8*)(obp0 + k0 + lq * 8);
      bf16x8 ab1 = *(const bf16x8*)(obp1 + k0 + lq * 8);
      #pragma unroll
      for (int t = 0; t < 6; ++t) {
        bf16x8 w = *(const bf16x8*)(Qt + (size_t)(cbase + t * 16 + lr) * 256 + k0 + lq * 8);
        bool useoq = (cbase + t * 16) < 512;
        acc[0][t] = __builtin_amdgcn_mfma_f32_16x16x32_bf16(useoq ? aq0 : ab0, w, acc[0][t], 0, 0, 0);
        acc[1][t] = __builtin_amdgcn_mfma_f32_16x16x32_bf16(useoq ? aq1 : ab1, w, acc[1][t], 0, 0, 0);
      }
    }
    #pragma unroll
    for (int t = 0; t < 6; ++t) {
      int colt = cbase + t * 16 + lr;
      float bv = qkvbias[colt];
      #pragma unroll
      for (int ti = 0; ti < 2; ++ti)
        #pragma unroll
        for (int rr = 0; rr < 4; ++rr)
          qkvout[(size_t)(m0 + ti * 16 + lq * 4 + rr) * 768 + colt] = f2bf(acc[ti][t][rr] + bv);
    }
  }
}

// ---------------------------------------------------------------------------
// MFMA self-attention. Block per (b,h,half).
// ---------------------------------------------------------------------------
__launch_bounds__(256)
__global__ void attn3_kernel(const short* __restrict__ qkv, short* __restrict__ O) {
  __shared__ short Kb[304][40];
  __shared__ short Vt[32][328];
  __shared__ short Pw[4][16][328];
  const int half = blockIdx.x & 1, bh = blockIdx.x >> 1;
  const int h = bh & 7, b = bh >> 3;
  const int tid = threadIdx.x;
  const short* QKVb = qkv + (size_t)b * LQ_ * 768;
  for (int idx = tid; idx < 304 * 4; idx += 256) {
    int row = idx >> 2, seg = (idx & 3) * 8;
    bf16x8 v = (row < 300) ? *(const bf16x8*)(QKVb + (size_t)row * 768 + 256 + h * 32 + seg)
                           : (bf16x8){0,0,0,0,0,0,0,0};
    *(bf16x8*)&Kb[row][seg] = v;
  }
  for (int idx = tid; idx < 300 * 4; idx += 256) {
    int row = idx >> 2, seg = (idx & 3) * 8;
    bf16x8 v = *(const bf16x8*)(QKVb + (size_t)row * 768 + 512 + h * 32 + seg);
    #pragma unroll
    for (int j = 0; j < 8; ++j) Vt[seg + j][row] = v[j];
  }
  for (int idx = tid; idx < 32 * 20; idx += 256) Vt[idx / 20][300 + idx % 20] = 0;
  for (int idx = tid; idx < 4 * 16 * 16; idx += 256)
    Pw[idx >> 8][(idx >> 4) & 15][304 + (idx & 15)] = 0;
  __syncthreads();

  const int wid = tid >> 6, lane = tid & 63;
  const int lr = lane & 15, lq = lane >> 4;
  short (*Pl)[328] = Pw[wid];
  const float scale = 0.17677669529663687f;

  for (int qt = wid; qt < 10; qt += 4) {
    const int q0 = half * 150 + qt * 16;
    int qrow = q0 + lr; if (qrow > 299) qrow = 299;
    bf16x8 af_q = *(const bf16x8*)(QKVb + (size_t)qrow * 768 + h * 32 + lq * 8);
    f32x4 s[19];
    #pragma unroll
    for (int t = 0; t < 19; ++t) {
      bf16x8 bk = *(const bf16x8*)&Kb[t * 16 + lr][lq * 8];
      s[t] = __builtin_amdgcn_mfma_f32_16x16x32_bf16(af_q, bk, (f32x4){0.f,0.f,0.f,0.f}, 0, 0, 0);
    }
    #pragma unroll
    for (int t = 0; t < 19; ++t)
      #pragma unroll
      for (int r = 0; r < 4; ++r) s[t][r] *= scale;
    if (lr >= 12) { s[18][0] = s[18][1] = s[18][2] = s[18][3] = -1e30f; }
    float l[4];
    #pragma unroll
    for (int r = 0; r < 4; ++r) {
      float mm = -1e30f;
      #pragma unroll
      for (int t = 0; t < 19; ++t) mm = fmaxf(mm, s[t][r]);
      #pragma unroll
      for (int x = 1; x < 16; x <<= 1) mm = fmaxf(mm, __shfl_xor(mm, x));
      float ll = 0.f;
      #pragma unroll
      for (int t = 0; t < 19; ++t) { float p = __expf(s[t][r] - mm); s[t][r] = p; ll += p; }
      #pragma unroll
      for (int x = 1; x < 16; x <<= 1) ll += __shfl_xor(ll, x);
      l[r] = ll;
    }
    #pragma unroll
    for (int t = 0; t < 19; ++t)
      #pragma unroll
      for (int r = 0; r < 4; ++r) Pl[lq * 4 + r][t * 16 + lr] = f2bf(s[t][r]);
    f32x4 o0 = (f32x4){0.f,0.f,0.f,0.f}, o1 = (f32x4){0.f,0.f,0.f,0.f};
    #pragma unroll
    for (int c = 0; c < 10; ++c) {
      bf16x8 ap = *(const bf16x8*)&Pl[lr][c * 32 + lq * 8];
      bf16x8 v0 = *(const bf16x8*)&Vt[lr][c * 32 + lq * 8];
      bf16x8 v1 = *(const bf16x8*)&Vt[16 + lr][c * 32 + lq * 8];
      o0 = __builtin_amdgcn_mfma_f32_16x16x32_bf16(ap, v0, o0, 0, 0, 0);
      o1 = __builtin_amdgcn_mfma_f32_16x16x32_bf16(ap, v1, o1, 0, 0, 0);
    }
    #pragma unroll
    for (int r = 0; r < 4; ++r) {
      int q = q0 + lq * 4 + r;
      if (q >= 300) continue;
      float inv = 1.f / l[r];
      size_t ob = (size_t)(b * LQ_ + q) * 256 + h * 32;
      O[ob + lr]      = f2bf(o0[r] * inv);
      O[ob + 16 + lr] = f2bf(o1[r] * inv);
    }
  }
}

// ---------------------------------------------------------------------------
// tail_fused: sow+LN+off | deform | gate+LN | ffn+LN (+scores) | [pb] | fdr
// (+lqe) | [next-layer qp+qkv].  Block owns 32 rows; all phases row-local.
// LDS arena overlays phase buffers; intermediates never touch global.
// ---------------------------------------------------------------------------
__launch_bounds__(512)
__global__ void tail_fused(
    const short* __restrict__ attnO,
    const short* __restrict__ sowt, const float* __restrict__ sob,
    const float* __restrict__ n1g, const float* __restrict__ n1b,
    const float* __restrict__ qpin,
    const short* __restrict__ offwt, const float* __restrict__ offb,
    const void*  __restrict__ memv, const float* __restrict__ refc,
    const short* __restrict__ gatet, const float* __restrict__ gateb,
    const float* __restrict__ gng, const float* __restrict__ gnb,
    const short* __restrict__ ff1t, const float* __restrict__ ff1b,
    const short* __restrict__ ff2t, const float* __restrict__ ff2b,
    const float* __restrict__ n3g, const float* __restrict__ n3b,
    float* __restrict__ out_prev, float* __restrict__ output, short* __restrict__ outbf,
    const short* __restrict__ bb1t, const float* __restrict__ bb1b,
    const short* __restrict__ bb2t, const float* __restrict__ bb2b,
    const short* __restrict__ bb3t, const float* __restrict__ bb3b,
    const float* __restrict__ cprev, float* __restrict__ ccur,
    float* __restrict__ refinit, float* __restrict__ refn,
    const short* __restrict__ pb1t, const float* __restrict__ pb1b,
    const short* __restrict__ pb2t, const float* __restrict__ pb2b,
    const short* __restrict__ pb3t, const float* __restrict__ pb3b,
    const short* __restrict__ sct, const float* __restrict__ scb,
    const float* __restrict__ lw1, const float* __restrict__ lb1,
    const float* __restrict__ lw2, const float* __restrict__ lb2,
    float* __restrict__ outp,
    const float* __restrict__ qpW1, const float* __restrict__ qpB1,
    const short* __restrict__ qp2t, const float* __restrict__ qpB2,
    const short* __restrict__ Qt, const float* __restrict__ qkvbias,
    float* __restrict__ qpout, short* __restrict__ qkvout,
    int layer0, int last, int bf16mem) {
  __shared__ __align__(16) char u0[66560];
  __shared__ __align__(16) float offl[32][288];
  __shared__ __align__(16) float t2s[32][256];   // deform t2 -> later scores
  __shared__ __align__(16) short tbo[32][264];   // deform tbf -> later oq
  __shared__ float ssum[32][8];
  __shared__ float ssq[32][8];
  __shared__ float projs[33];
  const int m0 = blockIdx.x * 32;
  const int tid = threadIdx.x, wid = tid >> 6, lane = tid & 63;
  const int lr = lane & 15, lq = lane >> 4;
  if (tid < 33) {
    float v;
    if (tid == 0) v = -4.f;
    else if (tid == 32) v = 4.f;
    else if (tid == 16) v = 0.f;
    else if (tid < 16) v = 1.f - powf(3.f, (float)(16 - tid) * (1.f / 15.f));
    else v = powf(3.f, (float)(tid - 16) * (1.f / 15.f)) - 1.f;
    projs[tid] = v;
  }

  // ================= S: sow GEMM + LN + off GEMM =================
  {
    short (*oqs)[264] = (short(*)[264])u0;
    const int cw = wid * 32;
    f32x4 acc[2][2];
    #pragma unroll
    for (int ti = 0; ti < 2; ++ti)
      #pragma unroll
      for (int t = 0; t < 2; ++t) acc[ti][t] = (f32x4){0.f, 0.f, 0.f, 0.f};
    #pragma unroll 4
    for (int k0 = 0; k0 < 256; k0 += 32) {
      bf16x8 a0 = *(const bf16x8*)(attnO + (size_t)(m0 + lr) * 256 + k0 + lq * 8);
      bf16x8 a1 = *(const bf16x8*)(attnO + (size_t)(m0 + 16 + lr) * 256 + k0 + lq * 8);
      #pragma unroll
      for (int t = 0; t < 2; ++t) {
        bf16x8 w = *(const bf16x8*)(sowt + (size_t)(cw + t * 16 + lr) * 256 + k0 + lq * 8);
        acc[0][t] = __builtin_amdgcn_mfma_f32_16x16x32_bf16(a0, w, acc[0][t], 0, 0, 0);
        acc[1][t] = __builtin_amdgcn_mfma_f32_16x16x32_bf16(a1, w, acc[1][t], 0, 0, 0);
      }
    }
    float s[2][4], q[2][4];
    #pragma unroll
    for (int ti = 0; ti < 2; ++ti)
      #pragma unroll
      for (int rr = 0; rr < 4; ++rr) { s[ti][rr] = 0.f; q[ti][rr] = 0.f; }
    #pragma unroll
    for (int t = 0; t < 2; ++t) {
      int col = cw + t * 16 + lr;
      float bv = sob[col];
      #pragma unroll
      for (int ti = 0; ti < 2; ++ti)
        #pragma unroll
        for (int rr = 0; rr < 4; ++rr) {
          int rowg = m0 + ti * 16 + lq * 4 + rr;
          float x = acc[ti][t][rr] + bv + output[(size_t)rowg * 256 + col];
          acc[ti][t][rr] = x;
          s[ti][rr] += x; q[ti][rr] += x * x;
        }
    }
    #pragma unroll
    for (int m = 1; m < 16; m <<= 1)
      #pragma unroll
      for (int ti = 0; ti < 2; ++ti)
        #pragma unroll
        for (int rr = 0; rr < 4; ++rr) {
          s[ti][rr] += __shfl_xor(s[ti][rr], m);
          q[ti][rr] += __shfl_xor(q[ti][rr], m);
        }
    if (lr == 0)
      #pragma unroll
      for (int ti = 0; ti < 2; ++ti)
        #pragma unroll
        for (int rr = 0; rr < 4; ++rr) {
          ssum[ti * 16 + lq * 4 + rr][wid] = s[ti][rr];
          ssq[ti * 16 + lq * 4 + rr][wid] = q[ti][rr];
        }
    __syncthreads();
    float mu[2][4], rs[2][4];
    #pragma unroll
    for (int ti = 0; ti < 2; ++ti)
      #pragma unroll
      for (int rr = 0; rr < 4; ++rr) {
        int rl = ti * 16 + lq * 4 + rr;
        float sm = 0.f, sq = 0.f;
        #pragma unroll
        for (int w8 = 0; w8 < 8; ++w8) { sm += ssum[rl][w8]; sq += ssq[rl][w8]; }
        float m_ = sm * (1.f / 256.f);
        float var = sq * (1.f / 256.f) - m_ * m_;
        mu[ti][rr] = m_; rs[ti][rr] = rsqrtf(var + 1e-5f);
      }
    #pragma unroll
    for (int t = 0; t < 2; ++t) {
      int col = cw + t * 16 + lr;
      float g = gng[col], be = gnb ? n1b[col] : n1b[col];
      g = n1g[col]; be = n1b[col];
      #pragma unroll
      for (int ti = 0; ti < 2; ++ti)
        #pragma unroll
        for (int rr = 0; rr < 4; ++rr) {
          int rl = ti * 16 + lq * 4 + rr;
          size_t idx = (size_t)(m0 + rl) * 256 + col;
          float v = (acc[ti][t][rr] - mu[ti][rr]) * rs[ti][rr] * g + be;
          output[idx] = v;
          outbf[idx] = f2bf(v);
          oqs[rl][col] = f2bf(v + qpin[idx]);
        }
    }
    __syncthreads();
    // off GEMM: 288 cols = 18 tiles over 8 waves -> offl (LDS)
    f32x4 oacc[2][3];
    #pragma unroll
    for (int ti = 0; ti < 2; ++ti)
      #pragma unroll
      for (int j = 0; j < 3; ++j) oacc[ti][j] = (f32x4){0.f, 0.f, 0.f, 0.f};
    #pragma unroll 2
    for (int k0 = 0; k0 < 256; k0 += 32) {
      bf16x8 a0 = *(const bf16x8*)&oqs[lr][k0 + lq * 8];
      bf16x8 a1 = *(const bf16x8*)&oqs[16 + lr][k0 + lq * 8];
      #pragma unroll
      for (int j = 0; j < 3; ++j) {
        int tile = wid + j * 8;
        int trow = (tile < 18) ? tile * 16 + lr : 0;
        bf16x8 w = *(const bf16x8*)(offwt + (size_t)trow * 256 + k0 + lq * 8);
        oacc[0][j] = __builtin_amdgcn_mfma_f32_16x16x32_bf16(a0, w, oacc[0][j], 0, 0, 0);
        oacc[1][j] = __builtin_amdgcn_mfma_f32_16x16x32_bf16(a1, w, oacc[1][j], 0, 0, 0);
      }
    }
    #pragma unroll
    for (int j = 0; j < 3; ++j) {
      int tile = wid + j * 8;
      if (tile >= 18) continue;
      int col = tile * 16 + lr;
      float bv = offb[col];
      #pragma unroll
      for (int ti = 0; ti < 2; ++ti)
        #pragma unroll
        for (int rr = 0; rr < 4; ++rr)
          offl[ti * 16 + lq * 4 + rr][col] = oacc[ti][j][rr] + bv;
    }
  }
  __syncthreads();

  // ================= D: deform (LDS offl -> t2s/tbo) =================
  {
    const int sub = tid >> 8;
    const int it = tid & 255;
    const int h = it >> 5, c = it & 31;
    for (int rp = 0; rp < 32; rp += 2) {
      int r = rp + sub;
      int row = m0 + r;
      int b = row / LQ_;
      float rx = refc[row * 4 + 0], ry = refc[row * 4 + 1];
      float rw = refc[row * 4 + 2], rh = refc[row * 4 + 3];
      const float* awp = &offl[r][192 + h * SUMP_];
      float wv[SUMP_];
      float wmax = -1e30f;
      #pragma unroll
      for (int p = 0; p < SUMP_; ++p) { wv[p] = awp[p]; wmax = fmaxf(wmax, wv[p]); }
      float wsum = 0.f;
      #pragma unroll
      for (int p = 0; p < SUMP_; ++p) { wv[p] = __expf(wv[p] - wmax); wsum += wv[p]; }
      const float winv = 1.f / wsum;
      const float* op = &offl[r][h * (SUMP_ * 2)];
      float acc = 0.f;
      #pragma unroll
      for (int p = 0; p < SUMP_; ++p) {
        const int lvl = p >> 2;
        const int Wl = (lvl == 0) ? 80 : ((lvl == 1) ? 40 : 20);
        const int s0 = (lvl == 0) ? 0 : ((lvl == 1) ? 6400 : 8000);
        float lx = rx + op[2 * p]     * 0.125f * rw;
        float ly = ry + op[2 * p + 1] * 0.125f * rh;
        float x = lx * Wl - 0.5f, y = ly * Wl - 0.5f;
        float xf = floorf(x), yf = floorf(y);
        int x0 = (int)xf, y0 = (int)yf;
        float wx = x - xf, wy = y - yf;
        int x0c = min(max(x0, 0), Wl - 1), x1c = min(max(x0 + 1, 0), Wl - 1);
        int y0c = min(max(y0, 0), Wl - 1), y1c = min(max(y0 + 1, 0), Wl - 1);
        float wx0 = (x0 >= 0 && x0 < Wl) ? (1.f - wx) : 0.f;
        float wx1 = (x0 + 1 >= 0 && x0 + 1 < Wl) ? wx : 0.f;
        float wy0 = (y0 >= 0 && y0 < Wl) ? (1.f - wy) : 0.f;
        float wy1 = (y0 + 1 >= 0 && y0 + 1 < Wl) ? wy : 0.f;
        float v;
        if (bf16mem) {
          const short* mb = (const short*)memv + ((size_t)(b * 8 + h) * STOT_ + s0) * 32 + c;
          v = wx0 * wy0 * bf2f(mb[(size_t)(y0c * Wl + x0c) * 32])
            + wx1 * wy0 * bf2f(mb[(size_t)(y0c * Wl + x1c) * 32])
            + wx0 * wy1 * bf2f(mb[(size_t)(y1c * Wl + x0c) * 32])
            + wx1 * wy1 * bf2f(mb[(size_t)(y1c * Wl + x1c) * 32]);
        } else {
          const float* mb = (const float*)memv + (size_t)b * STOT_ * 256 + (size_t)s0 * 256 + h * 32 + c;
          v = wx0 * wy0 * mb[(size_t)(y0c * Wl + x0c) * 256]
            + wx1 * wy0 * mb[(size_t)(y0c * Wl + x1c) * 256]
            + wx0 * wy1 * mb[(size_t)(y1c * Wl + x0c) * 256]
            + wx1 * wy1 * mb[(size_t)(y1c * Wl + x1c) * 256];
        }
        acc += wv[p] * winv * v;
      }
      t2s[r][it] = acc;
      tbo[r][it] = f2bf(acc);
    }
  }
  __syncthreads();

  // ================= G: gate GEMM + sigmoid + gated-add + LN =================
  {
    float (*sg)[520] = (float(*)[520])u0;
    f32x4 acc[2][4];
    #pragma unroll
    for (int ti = 0; ti < 2; ++ti)
      #pragma unroll
      for (int t = 0; t < 4; ++t) acc[ti][t] = (f32x4){0.f, 0.f, 0.f, 0.f};
    #pragma unroll 2
    for (int k0 = 0; k0 < 256; k0 += 32) {
      bf16x8 a0 = *(const bf16x8*)(outbf + (size_t)(m0 + lr) * 256 + k0 + lq * 8);
      bf16x8 a1 = *(const bf16x8*)(outbf + (size_t)(m0 + 16 + lr) * 256 + k0 + lq * 8);
      #pragma unroll
      for (int t = 0; t < 4; ++t) {
        bf16x8 w = *(const bf16x8*)(gatet + (size_t)(wid * 64 + t * 16 + lr) * 512 + k0 + lq * 8);
        acc[0][t] = __builtin_amdgcn_mfma_f32_16x16x32_bf16(a0, w, acc[0][t], 0, 0, 0);
        acc[1][t] = __builtin_amdgcn_mfma_f32_16x16x32_bf16(a1, w, acc[1][t], 0, 0, 0);
      }
    }
    #pragma unroll 2
    for (int k0 = 256; k0 < 512; k0 += 32) {
      int ko = k0 - 256;
      bf16x8 a0 = *(const bf16x8*)&tbo[lr][ko + lq * 8];
      bf16x8 a1 = *(const bf16x8*)&tbo[16 + lr][ko + lq * 8];
      #pragma unroll
      for (int t = 0; t < 4; ++t) {
        bf16x8 w = *(const bf16x8*)(gatet + (size_t)(wid * 64 + t * 16 + lr) * 512 + k0 + lq * 8);
        acc[0][t] = __builtin_amdgcn_mfma_f32_16x16x32_bf16(a0, w, acc[0][t], 0, 0, 0);
        acc[1][t] = __builtin_amdgcn_mfma_f32_16x16x32_bf16(a1, w, acc[1][t], 0, 0, 0);
      }
    }
    #pragma unroll
    for (int t = 0; t < 4; ++t) {
      int col = wid * 64 + t * 16 + lr;
      float bv = gateb[col];
      #pragma unroll
      for (int ti = 0; ti < 2; ++ti)
        #pragma unroll
        for (int rr = 0; rr < 4; ++rr) {
          int rl = ti * 16 + lq * 4 + rr;
          sg[rl][col] = 1.f / (1.f + __expf(-(acc[ti][t][rr] + bv)));
        }
    }
    __syncthreads();
    #pragma unroll
    for (int it = 0; it < 4; ++it) {
      int rl = wid + it * 8;
      int rowg = m0 + rl;
      int c = lane * 4;
      float4 o4 = *(const float4*)(output + (size_t)rowg * 256 + c);
      float4 t4 = *(const float4*)&t2s[rl][c];
      float4 g1 = *(const float4*)&sg[rl][c];
      float4 g2 = *(const float4*)&sg[rl][256 + c];
      float x0 = g1.x * o4.x + g2.x * t4.x;
      float x1 = g1.y * o4.y + g2.y * t4.y;
      float x2 = g1.z * o4.z + g2.z * t4.z;
      float x3 = g1.w * o4.w + g2.w * t4.w;
      float s = x0 + x1 + x2 + x3;
      float q = x0 * x0 + x1 * x1 + x2 * x2 + x3 * x3;
      #pragma unroll
      for (int o = 32; o; o >>= 1) { s += __shfl_xor(s, o); q += __shfl_xor(q, o); }
      float mu = s * (1.f / 256.f);
      float var = q * (1.f / 256.f) - mu * mu;
      float rs = rsqrtf(var + 1e-5f);
      float4 ga = *(const float4*)(gng + c);
      float4 be = *(const float4*)(gnb + c);
      float v0 = (x0 - mu) * rs * ga.x + be.x;
      float v1 = (x1 - mu) * rs * ga.y + be.y;
      float v2 = (x2 - mu) * rs * ga.z + be.z;
      float v3 = (x3 - mu) * rs * ga.w + be.w;
      float4 vo; vo.x = v0; vo.y = v1; vo.z = v2; vo.w = v3;
      *(float4*)(output + (size_t)rowg * 256 + c) = vo;
      short4 vs; vs.x = f2bf(v0); vs.y = f2bf(v1); vs.z = f2bf(v2); vs.w = f2bf(v3);
      *(short4*)(outbf + (size_t)rowg * 256 + c) = vs;
    }
  }
  __syncthreads();

  // ================= F: ffn + LN (+ scores on last) =================
  {
    short (*hid)[1032] = (short(*)[1032])u0;
    {
      f32x4 acc[2][8];
      #pragma unroll
      for (int ti = 0; ti < 2; ++ti)
        #pragma unroll
        for (int t = 0; t < 8; ++t) acc[ti][t] = (f32x4){0.f, 0.f, 0.f, 0.f};
      #pragma unroll 2
      for (int k0 = 0; k0 < 256; k0 += 32) {
        bf16x8 a0 = *(const bf16x8*)(outbf + (size_t)(m0 + lr) * 256 + k0 + lq * 8);
        bf16x8 a1 = *(const bf16x8*)(outbf + (size_t)(m0 + 16 + lr) * 256 + k0 + lq * 8);
        #pragma unroll
        for (int t = 0; t < 8; ++t) {
          bf16x8 w = *(const bf16x8*)(ff1t + (size_t)(wid * 128 + t * 16 + lr) * 256 + k0 + lq * 8);
          acc[0][t] = __builtin_amdgcn_mfma_f32_16x16x32_bf16(a0, w, acc[0][t], 0, 0, 0);
          acc[1][t] = __builtin_amdgcn_mfma_f32_16x16x32_bf16(a1, w, acc[1][t], 0, 0, 0);
        }
      }
      #pragma unroll
      for (int t = 0; t < 8; ++t) {
        int col = wid * 128 + t * 16 + lr;
        float bv = ff1b[col];
        #pragma unroll
        for (int ti = 0; ti < 2; ++ti)
          #pragma unroll
          for (int rr = 0; rr < 4; ++rr)
            hid[ti * 16 + lq * 4 + rr][col] = f2bf(fmaxf(acc[ti][t][rr] + bv, 0.f));
      }
    }
    __syncthreads();
    const int cw = wid * 32;
    f32x4 acc[2][2];
    #pragma unroll
    for (int ti = 0; ti < 2; ++ti)
      #pragma unroll
      for (int t = 0; t < 2; ++t) acc[ti][t] = (f32x4){0.f, 0.f, 0.f, 0.f};
    #pragma unroll 4
    for (int k0 = 0; k0 < 1024; k0 += 32) {
      bf16x8 a0 = *(const bf16x8*)&hid[lr][k0 + lq * 8];
      bf16x8 a1 = *(const bf16x8*)&hid[16 + lr][k0 + lq * 8];
      #pragma unroll
      for (int t = 0; t < 2; ++t) {
        bf16x8 w = *(const bf16x8*)(ff2t + (size_t)(cw + t * 16 + lr) * 1024 + k0 + lq * 8);
        acc[0][t] = __builtin_amdgcn_mfma_f32_16x16x32_bf16(a0, w, acc[0][t], 0, 0, 0);
        acc[1][t] = __builtin_amdgcn_mfma_f32_16x16x32_bf16(a1, w, acc[1][t], 0, 0, 0);
      }
    }
    float s[2][4], q[2][4];
    #pragma unroll
    for (int ti = 0; ti < 2; ++ti)
      #pragma unroll
      for (int rr = 0; rr < 4; ++rr) { s[ti][rr] = 0.f; q[ti][rr] = 0.f; }
    #pragma unroll
    for (int t = 0; t < 2; ++t) {
      int col = cw + t * 16 + lr;
      float bv = ff2b[col];
      #pragma unroll
      for (int ti = 0; ti < 2; ++ti)
        #pragma unroll
        for (int rr = 0; rr < 4; ++rr) {
          int rowg = m0 + ti * 16 + lq * 4 + rr;
          float x = acc[ti][t][rr] + bv + output[(size_t)rowg * 256 + col];
          x = fminf(fmaxf(x, -65504.f), 65504.f);
          acc[ti][t][rr] = x;
          s[ti][rr] += x; q[ti][rr] += x * x;
        }
    }
    #pragma unroll
    for (int m = 1; m < 16; m <<= 1)
      #pragma unroll
      for (int ti = 0; ti < 2; ++ti)
        #pragma unroll
        for (int rr = 0; rr < 4; ++rr) {
          s[ti][rr] += __shfl_xor(s[ti][rr], m);
          q[ti][rr] += __shfl_xor(q[ti][rr], m);
        }
    if (lr == 0)
      #pragma unroll
      for (int ti = 0; ti < 2; ++ti)
        #pragma unroll
        for (int rr = 0; rr < 4; ++rr) {
          ssum[ti * 16 + lq * 4 + rr][wid] = s[ti][rr];
          ssq[ti * 16 + lq * 4 + rr][wid] = q[ti][rr];
        }
    __syncthreads();
    float mu[2][4], rs[2][4];
    #pragma unroll
    for (int ti = 0; ti < 2; ++ti)
      #pragma unroll
      for (int rr = 0; rr < 4; ++rr) {
        int rl = ti * 16 + lq * 4 + rr;
        float sm = 0.f, sq = 0.f;
        #pragma unroll
        for (int w8 = 0; w8 < 8; ++w8) { sm += ssum[rl][w8]; sq += ssq[rl][w8]; }
        float m_ = sm * (1.f / 256.f);
        float var = sq * (1.f / 256.f) - m_ * m_;
        mu[ti][rr] = m_; rs[ti][rr] = rsqrtf(var + 1e-5f);
      }
    #pragma unroll
    for (int t = 0; t < 2; ++t) {
      int col = cw + t * 16 + lr;
      float g = n3g[col], be = n3b[col];
      #pragma unroll
      for (int ti = 0; ti < 2; ++ti)
        #pragma unroll
        for (int rr = 0; rr < 4; ++rr) {
          int rl = ti * 16 + lq * 4 + rr;
          size_t idx = (size_t)(m0 + rl) * 256 + col;
          float v = (acc[ti][t][rr] - mu[ti][rr]) * rs[ti][rr] * g + be;
          output[idx] = v;
          short vb = f2bf(v);
          outbf[idx] = vb;
          float po = out_prev[idx];
          tbo[rl][col] = f2bf(v + po);     // oq for fdr (LDS)
          out_prev[idx] = v;
          if (last) hid[rl][col] = vb;
        }
    }
    if (last) {
      __syncthreads();
      f32x4 sacc[2];
      sacc[0] = (f32x4){0.f, 0.f, 0.f, 0.f};
      sacc[1] = (f32x4){0.f, 0.f, 0.f, 0.f};
      int trow = (wid < 5) ? wid * 16 + lr : 0;
      #pragma unroll 2
      for (int k0 = 0; k0 < 256; k0 += 32) {
        bf16x8 a0 = *(const bf16x8*)&hid[lr][k0 + lq * 8];
        bf16x8 a1 = *(const bf16x8*)&hid[16 + lr][k0 + lq * 8];
        bf16x8 w = *(const bf16x8*)(sct + (size_t)trow * 256 + k0 + lq * 8);
        sacc[0] = __builtin_amdgcn_mfma_f32_16x16x32_bf16(a0, w, sacc[0], 0, 0, 0);
        sacc[1] = __builtin_amdgcn_mfma_f32_16x16x32_bf16(a1, w, sacc[1], 0, 0, 0);
      }
      __syncthreads();   // t2s dead (gate done); safe to overwrite as scores
      if (wid < 5) {
        int col = wid * 16 + lr;
        float bv = scb[col];
        #pragma unroll
        for (int ti = 0; ti < 2; ++ti)
          #pragma unroll
          for (int rr = 0; rr < 4; ++rr)
            t2s[ti * 16 + lq * 4 + rr][col] = sacc[ti][rr] + bv;
      }
    }
  }
  __syncthreads();

  // ================= P: pre-bbox (layer 0 only) =================
  if (layer0) {
    short (*h1)[264] = (short(*)[264])u0;
    short (*h2)[264] = (short(*)[264])(u0 + 16896);
    {
      f32x4 acc[2][2];
      #pragma unroll
      for (int ti = 0; ti < 2; ++ti)
        #pragma unroll
        for (int t = 0; t < 2; ++t) acc[ti][t] = (f32x4){0.f, 0.f, 0.f, 0.f};
      #pragma unroll 2
      for (int k0 = 0; k0 < 256; k0 += 32) {
        bf16x8 a0 = *(const bf16x8*)(outbf + (size_t)(m0 + lr) * 256 + k0 + lq * 8);
        bf16x8 a1 = *(const bf16x8*)(outbf + (size_t)(m0 + 16 + lr) * 256 + k0 + lq * 8);
        #pragma unroll
        for (int t = 0; t < 2; ++t) {
          bf16x8 w = *(const bf16x8*)(pb1t + (size_t)(wid * 32 + t * 16 + lr) * 256 + k0 + lq * 8);
          acc[0][t] = __builtin_amdgcn_mfma_f32_16x16x32_bf16(a0, w, acc[0][t], 0, 0, 0);
          acc[1][t] = __builtin_amdgcn_mfma_f32_16x16x32_bf16(a1, w, acc[1][t], 0, 0, 0);
        }
      }
      #pragma unroll
      for (int t = 0; t < 2; ++t) {
        int col = wid * 32 + t * 16 + lr;
        float bv = pb1b[col];
        #pragma unroll
        for (int ti = 0; ti < 2; ++ti)
          #pragma unroll
          for (int rr = 0; rr < 4; ++rr) {
            float v = acc[ti][t][rr] + bv;
            v = v / (1.f + __expf(-v));
            h1[ti * 16 + lq * 4 + rr][col] = f2bf(v);
          }
      }
    }
    __syncthreads();
    {
      f32x4 acc[2][2];
      #pragma unroll
      for (int ti = 0; ti < 2; ++ti)
        #pragma unroll
        for (int t = 0; t < 2; ++t) acc[ti][t] = (f32x4){0.f, 0.f, 0.f, 0.f};
      #pragma unroll 2
      for (int k0 = 0; k0 < 256; k0 += 32) {
        bf16x8 a0 = *(const bf16x8*)&h1[lr][k0 + lq * 8];
        bf16x8 a1 = *(const bf16x8*)&h1[16 + lr][k0 + lq * 8];
        #pragma unroll
        for (int t = 0; t < 2; ++t) {
          bf16x8 w = *(const bf16x8*)(pb2t + (size_t)(wid * 32 + t * 16 + lr) * 256 + k0 + lq * 8);
          acc[0][t] = __builtin_amdgcn_mfma_f32_16x16x32_bf16(a0, w, acc[0][t], 0, 0, 0);
          acc[1][t] = __builtin_amdgcn_mfma_f32_16x16x32_bf16(a1, w, acc[1][t], 0, 0, 0);
        }
      }
      #pragma unroll
      for (int t = 0; t < 2; ++t) {
        int col = wid * 32 + t * 16 + lr;
        float bv = pb2b[col];
        #pragma unroll
        for (int ti = 0; ti < 2; ++ti)
          #pragma unroll
          for (int rr = 0; rr < 4; ++rr) {
            float v = acc[ti][t][rr] + bv;
            v = v / (1.f + __expf(-v));
            h2[ti * 16 + lq * 4 + rr][col] = f2bf(v);
          }
      }
    }
    __syncthreads();
    if (wid < 2) {
      const int rbase = wid * 16;
      f32x4 acc = (f32x4){0.f, 0.f, 0.f, 0.f};
      const short* wp = pb3t + (size_t)((lr < 4) ? lr : 0) * 256;
      #pragma unroll 2
      for (int k0 = 0; k0 < 256; k0 += 32) {
        bf16x8 a = *(const bf16x8*)&h2[rbase + lr][k0 + lq * 8];
        bf16x8 w = *(const bf16x8*)(wp + k0 + lq * 8);
        acc = __builtin_amdgcn_mfma_f32_16x16x32_bf16(a, w, acc, 0, 0, 0);
      }
      if (lr < 4) {
        float bv = pb3b[lr];
        #pragma unroll
        for (int rr = 0; rr < 4; ++rr) {
          int g = m0 + rbase + lq * 4 + rr;
          float pre = acc[rr] + bv;
          float x = fminf(fmaxf(refc[(size_t)g * 4 + lr], 1e-5f), 1.f - 1e-5f);
          float is = logf(x) - log1pf(-x);
          refinit[(size_t)g * 4 + lr] = 1.f / (1.f + __expf(-(pre + is)));
        }
      }
    }
    __syncthreads();
  }

  // ================= R: fdr chain (+ lqe on last) =================
  {
    short (*h1)[264]  = (short(*)[264])u0;
    short (*h2)[264]  = (short(*)[264])(u0 + 16896);
    float (*cor)[132] = (float(*)[132])(u0 + 33792);
    float (*statl)[20]= (float(*)[20])(u0 + 50688);
    float (*interb)[4]= (float(*)[4])(u0 + 53248);
    float *lqes       = (float*)(u0 + 53760);
    float (*dstl)[4]  = (float(*)[4])(u0 + 53888);
    {
      f32x4 acc[2][2];
      #pragma unroll
      for (int ti = 0; ti < 2; ++ti)
        #pragma unroll
        for (int t = 0; t < 2; ++t) acc[ti][t] = (f32x4){0.f, 0.f, 0.f, 0.f};
      #pragma unroll 2
      for (int k0 = 0; k0 < 256; k0 += 32) {
        bf16x8 a0 = *(const bf16x8*)&tbo[lr][k0 + lq * 8];
        bf16x8 a1 = *(const bf16x8*)&tbo[16 + lr][k0 + lq * 8];
        #pragma unroll
        for (int t = 0; t < 2; ++t) {
          bf16x8 w = *(const bf16x8*)(bb1t + (size_t)(wid * 32 + t * 16 + lr) * 256 + k0 + lq * 8);
          acc[0][t] = __builtin_amdgcn_mfma_f32_16x16x32_bf16(a0, w, acc[0][t], 0, 0, 0);
          acc[1][t] = __builtin_amdgcn_mfma_f32_16x16x32_bf16(a1, w, acc[1][t], 0, 0, 0);
        }
      }
      __syncthreads();   // ensure prior u0 readers done before h1 writes
      #pragma unroll
      for (int t = 0; t < 2; ++t) {
        int col = wid * 32 + t * 16 + lr;
        float bv = bb1b[col];
        #pragma unroll
        for (int ti = 0; ti < 2; ++ti)
          #pragma unroll
          for (int rr = 0; rr < 4; ++rr) {
            float v = acc[ti][t][rr] + bv;
            v = v / (1.f + __expf(-v));
            h1[ti * 16 + lq * 4 + rr][col] = f2bf(v);
          }
      }
    }
    __syncthreads();
    {
      f32x4 acc[2][2];
      #pragma unroll
      for (int ti = 0; ti < 2; ++ti)
        #pragma unroll
        for (int t = 0; t < 2; ++t) acc[ti][t] = (f32x4){0.f, 0.f, 0.f, 0.f};
      #pragma unroll 2
      for (int k0 = 0; k0 < 256; k0 += 32) {
        bf16x8 a0 = *(const bf16x8*)&h1[lr][k0 + lq * 8];
        bf16x8 a1 = *(const bf16x8*)&h1[16 + lr][k0 + lq * 8];
        #pragma unroll
        for (int t = 0; t < 2; ++t) {
          bf16x8 w = *(const bf16x8*)(bb2t + (size_t)(wid * 32 + t * 16 + lr) * 256 + k0 + lq * 8);
          acc[0][t] = __builtin_amdgcn_mfma_f32_16x16x32_bf16(a0, w, acc[0][t], 0, 0, 0);
          acc[1][t] = __builtin_amdgcn_mfma_f32_16x16x32_bf16(a1, w, acc[1][t], 0, 0, 0);
        }
      }
      #pragma unroll
      for (int t = 0; t < 2; ++t) {
        int col = wid * 32 + t * 16 + lr;
        float bv = bb2b[col];
        #pragma unroll
        for (int ti = 0; ti < 2; ++ti)
          #pragma unroll
          for (int rr = 0; rr < 4; ++rr) {
            float v = acc[ti][t][rr] + bv;
            v = v / (1.f + __expf(-v));
            h2[ti * 16 + lq * 4 + rr][col] = f2bf(v);
          }
      }
    }
    __syncthreads();
    {
      f32x4 acc[2][2];
      int col[2], wr[2];
      #pragma unroll
      for (int j = 0; j < 2; ++j) {
        acc[0][j] = (f32x4){0.f, 0.f, 0.f, 0.f};
        acc[1][j] = (f32x4){0.f, 0.f, 0.f, 0.f};
        col[j] = (wid + j * 8) * 16 + lr;
        wr[j] = (col[j] < 132) ? col[j] : 0;
      }
      #pragma unroll 2
      for (int k0 = 0; k0 < 256; k0 += 32) {
        bf16x8 a0 = *(const bf16x8*)&h2[lr][k0 + lq * 8];
        bf16x8 a1 = *(const bf16x8*)&h2[16 + lr][k0 + lq * 8];
        #pragma unroll
        for (int j = 0; j < 2; ++j) {
          bf16x8 w = *(const bf16x8*)(bb3t + (size_t)wr[j] * 256 + k0 + lq * 8);
          acc[0][j] = __builtin_amdgcn_mfma_f32_16x16x32_bf16(a0, w, acc[0][j], 0, 0, 0);
          acc[1][j] = __builtin_amdgcn_mfma_f32_16x16x32_bf16(a1, w, acc[1][j], 0, 0, 0);
        }
      }
      #pragma unroll
      for (int j = 0; j < 2; ++j) {
        if (col[j] >= 132) continue;
        float bv = bb3b[col[j]];
        #pragma unroll
        for (int ti = 0; ti < 2; ++ti)
          #pragma unroll
          for (int rr = 0; rr < 4; ++rr) {
            int rl = ti * 16 + lq * 4 + rr, g = m0 + rl;
            float v = acc[ti][j][rr] + bv + cprev[(size_t)g * 132 + col[j]];
            ccur[(size_t)g * 132 + col[j]] = v;
            cor[rl][col[j]] = v;
          }
      }
    }
    __syncthreads();
    if (tid < 128) {
      int r = tid >> 2, sd = tid & 3;
      const float* cp = &cor[r][sd * 33];
      float m = -1e30f;
      #pragma unroll
      for (int j = 0; j < 33; ++j) m = fmaxf(m, cp[j]);
      float t0 = -1e30f, t1 = -1e30f, t2v = -1e30f, t3 = -1e30f;
      float sum = 0.f, dot = 0.f;
      #pragma unroll
      for (int j = 0; j < 33; ++j) {
        float e = __expf(cp[j] - m);
        sum += e; dot += e * projs[j];
        if (last) {
          if (e > t0)      { t3 = t2v; t2v = t1; t1 = t0; t0 = e; }
          else if (e > t1) { t3 = t2v; t2v = t1; t1 = e; }
          else if (e > t2v){ t3 = t2v; t2v = e; }
          else if (e > t3) { t3 = e; }
        }
      }
      dstl[r][sd] = dot / sum;
      if (last) {
        float inv = 1.f / sum;
        float v0 = t0 * inv, v1 = t1 * inv, v2 = t2v * inv, v3 = t3 * inv;
        statl[r][sd * 5 + 0] = v0; statl[r][sd * 5 + 1] = v1;
        statl[r][sd * 5 + 2] = v2; statl[r][sd * 5 + 3] = v3;
        statl[r][sd * 5 + 4] = (v0 + v1 + v2 + v3) * 0.25f;
      }
    }
    __syncthreads();
    if (tid < 32) {
      int g = m0 + tid;
      float px = refinit[g * 4], py = refinit[g * 4 + 1];
      float qw = refinit[g * 4 + 2] * 0.25f, qh = refinit[g * 4 + 3] * 0.25f;
      float x1 = px - (2.f + dstl[tid][0]) * qw, y1 = py - (2.f + dstl[tid][1]) * qh;
      float x2 = px + (2.f + dstl[tid][2]) * qw, y2 = py + (2.f + dstl[tid][3]) * qh;
      float4 o; o.x = (x1 + x2) * 0.5f; o.y = (y1 + y2) * 0.5f; o.z = x2 - x1; o.w = y2 - y1;
      *(float4*)(refn + (size_t)g * 4) = o;
      if (last) { interb[tid][0] = o.x; interb[tid][1] = o.y; interb[tid][2] = o.z; interb[tid][3] = o.w; }
    }
    if (last) {
      #pragma unroll
      for (int it = 0; it < 4; ++it) {
        int row = wid * 4 + it;
        float sv = lb1[lane];
        #pragma unroll
        for (int i = 0; i < 20; ++i) sv += statl[row][i] * lw1[i * 64 + lane];
        float hv = sv / (1.f + __expf(-sv));
        float v = hv * lw2[lane];
        #pragma unroll
        for (int o = 32; o; o >>= 1) v += __shfl_xor(v, o);
        if (lane == 0) lqes[row] = v + lb2[0];
      }
      __syncthreads();
      for (int idx = tid; idx < 32 * 84; idx += 512) {
        int r = idx / 84, c = idx - r * 84;
        int g = m0 + r;
        outp[(size_t)g * 84 + c] = (c < 4) ? interb[r][c]
                                           : t2s[r][c - 4] + lqes[r];
      }
    }
  }

  // ================= Q: next-layer qp MLP + qkv GEMM =================
  if (!last) {
    __syncthreads();
    short* sh = (short*)u0;                       // [32*520]
    short (*oq2)[264] = (short(*)[264])(u0 + 33280);
    for (int i = tid; i < 32 * 512; i += 512) {
      int r = i >> 9, n = i & 511;
      float4 rv = *(const float4*)(refn + (size_t)(m0 + r) * 4);
      float v = qpB1[n] + rv.x * qpW1[n] + rv.y * qpW1[512 + n] + rv.z * qpW1[1024 + n]
              + rv.w * qpW1[1536 + n];
      v = v / (1.f + __expf(-v));
      sh[r * 520 + n] = f2bf(v);
    }
    __syncthreads();
    {
      f32x4 acc[2][2];
      #pragma unroll
      for (int ti = 0; ti < 2; ++ti)
        #pragma unroll
        for (int t = 0; t < 2; ++t) acc[ti][t] = (f32x4){0.f, 0.f, 0.f, 0.f};
      #pragma unroll 4
      for (int k0 = 0; k0 < 512; k0 += 32) {
        bf16x8 a0 = *(const bf16x8*)&sh[lr * 520 + k0 + lq * 8];
        bf16x8 a1 = *(const bf16x8*)&sh[(16 + lr) * 520 + k0 + lq * 8];
        #pragma unroll
        for (int t = 0; t < 2; ++t) {
          bf16x8 w = *(const bf16x8*)(qp2t + (size_t)(wid * 32 + t * 16 + lr) * 512 + k0 + lq * 8);
          acc[0][t] = __builtin_amdgcn_mfma_f32_16x16x32_bf16(a0, w, acc[0][t], 0, 0, 0);
          acc[1][t] = __builtin_amdgcn_mfma_f32_16x16x32_bf16(a1, w, acc[1][t], 0, 0, 0);
        }
      }
      #pragma unroll
      for (int t = 0; t < 2; ++t) {
        int col = wid * 32 + t * 16 + lr;
        float bv = qpB2[col];
        #pragma unroll
        for (int ti = 0; ti < 2; ++ti)
          #pragma unroll
          for (int rr = 0; rr < 4; ++rr) {
            int rl = ti * 16 + lq * 4 + rr;
            size_t idx = (size_t)(m0 + rl) * 256 + col;
            float v = fminf(fmaxf(acc[ti][t][rr] + bv, -10.f), 10.f);
            qpout[idx] = v;
            oq2[rl][col] = f2bf(v + output[idx]);
          }
      }
    }
    __syncthreads();
    {
      f32x4 acc[2][6];
      #pragma unroll
      for (int ti = 0; ti < 2; ++ti)
        #pragma unroll
        for (int t = 0; t < 6; ++t) acc[ti][t] = (f32x4){0.f, 0.f, 0.f, 0.f};
      const int cbase = wid * 96;
      const short* obp0 = outbf + (size_t)(m0 + lr) * 256;
      const short* obp1 = outbf + (size_t)(m0 + 16 + lr) * 256;
      #pragma unroll 2
      for (int k0 = 0; k0 < 256; k0 += 32) {
        bf16x8 aq0 = *(const bf16x8*)&oq2[lr][k0 + lq * 8];
        bf16x8 aq1 = *(const bf16x8*)&oq2[16 + lr][k0 + lq * 8];
        bf16x8 ab0 = *(const bf16x8*)(obp0 + k0 + lq * 8);
        bf16x8 ab1 = *(const bf16x8*)(obp1 + k0 + lq * 8);
        #pragma unroll
        for (int t = 0; t < 6; ++t) {
          bf16x8 w = *(const bf16x8*)(Qt + (size_t)(cbase + t * 16 + lr) * 256 + k0 + lq * 8);
          bool useoq = (cbase + t * 16) < 512;
          acc[0][t] = __builtin_amdgcn_mfma_f32_16x16x32_bf16(useoq ? aq0 : ab0, w, acc[0][t], 0, 0, 0);
          acc[1][t] = __builtin_amdgcn_mfma_f32_16x16x32_bf16(useoq ? aq1 : ab1, w, acc[1][t], 0, 0, 0);
        }
      }
      #pragma unroll
      for (int t = 0; t < 6; ++t) {
        int colt = cbase + t * 16 + lr;
        float bv = qkvbias[colt];
        #pragma unroll
        for (int ti = 0; ti < 2; ++ti)
          #pragma unroll
          for (int rr = 0; rr < 4; ++rr)
            qkvout[(size_t)(m0 + ti * 16 + lq * 4 + rr) * 768 + colt] = f2bf(acc[ti][t][rr] + bv);
      }
    }
  }
}

// ---------------------------------------------------------------------------
// host orchestration
// ---------------------------------------------------------------------------
static inline dim3 egrid(int n) { return dim3((n + 255) / 256); }

extern "C" void kernel_launch(void* const* d_in, const int* in_sizes, int n_in,
                              void* d_out, int out_size, void* d_ws, size_t ws_size,
                              hipStream_t stream) {
  const float* target     = (const float*)d_in[0];
  const float* ref_unact  = (const float*)d_in[1];
  const float* memory     = (const float*)d_in[2];
  const float* sa_qw = (const float*)d_in[3];  const float* sa_qb = (const float*)d_in[4];
  const float* sa_kw = (const float*)d_in[5];  const float* sa_kb = (const float*)d_in[6];
  const float* sa_vw = (const float*)d_in[7];  const float* sa_vb = (const float*)d_in[8];
  const float* sa_ow = (const float*)d_in[9];  const float* sa_ob = (const float*)d_in[10];
  const float* n1_g  = (const float*)d_in[11]; const float* n1_b  = (const float*)d_in[12];
  const float* off_w = (const float*)d_in[13]; const float* off_b = (const float*)d_in[14];
  const float* aw_w  = (const float*)d_in[15]; const float* aw_b  = (const float*)d_in[16];
  const float* gate_w= (const float*)d_in[17]; const float* gate_b= (const float*)d_in[18];
  const float* gn_g  = (const float*)d_in[19]; const float* gn_b  = (const float*)d_in[20];
  const float* ff1_w = (const float*)d_in[21]; const float* ff1_b = (const float*)d_in[22];
  const float* ff2_w = (const float*)d_in[23]; const float* ff2_b = (const float*)d_in[24];
  const float* n3_g  = (const float*)d_in[25]; const float* n3_b  = (const float*)d_in[26];
  const float* bb_w1 = (const float*)d_in[27]; const float* bb_b1 = (const float*)d_in[28];
  const float* bb_w2 = (const float*)d_in[29]; const float* bb_b2 = (const float*)d_in[30];
  const float* bb_w3 = (const float*)d_in[31]; const float* bb_b3 = (const float*)d_in[32];
  const float* sc_w  = (const float*)d_in[33]; const float* sc_b  = (const float*)d_in[34];
  const float* lqe_w1= (const float*)d_in[35]; const float* lqe_b1= (const float*)d_in[36];
  const float* lqe_w2= (const float*)d_in[37]; const float* lqe_b2= (const float*)d_in[38];
  const float* qp_w1 = (const float*)d_in[39]; const float* qp_b1 = (const float*)d_in[40];
  const float* qp_w2 = (const float*)d_in[41]; const float* qp_b2 = (const float*)d_in[42];
  const float* pb_w1 = (const float*)d_in[43]; const float* pb_b1 = (const float*)d_in[44];
  const float* pb_w2 = (const float*)d_in[45]; const float* pb_b2 = (const float*)d_in[46];
  const float* pb_w3 = (const float*)d_in[47]; const float* pb_b3 = (const float*)d_in[48];
  float* out = (float*)d_out;

  // ---- workspace: fp32 region ----
  float* ws = (float*)d_ws;
  size_t woff = 0;
  auto alloc = [&](size_t n) { float* p = ws + woff; woff += n; return p; };
  float* output   = alloc((size_t)R_ * D_);
  float* out_prev = alloc((size_t)R_ * D_);
  float* qp       = alloc((size_t)R_ * D_);
  float* U        = alloc((size_t)R_ * 512);  // qkv (bf16)
  float* corners0 = alloc((size_t)R_ * 4 * NBIN_);
  float* corners1 = alloc((size_t)R_ * 4 * NBIN_);
  float* refA     = alloc((size_t)R_ * 4);
  float* refB     = alloc((size_t)R_ * 4);
  float* ref_init = alloc((size_t)R_ * 4);
  float* qkvb     = alloc((size_t)NLAYERS_ * 768);
  float* offawb   = alloc((size_t)NLAYERS_ * 288);

  // ---- workspace: bf16 region ----
  short* sws = (short*)(ws + woff);
  size_t soff = 0;
  auto salloc = [&](size_t n) { short* p = sws + soff; soff += n; return p; };
  short* outbf = salloc((size_t)R_ * D_);
  short* tbf   = salloc((size_t)R_ * D_);
  short* qp2t  = salloc((size_t)256 * 512);
  short* sqkvt = salloc((size_t)NLAYERS_ * 768 * 256);
  short* sowt  = salloc((size_t)NLAYERS_ * 256 * 256);
  short* soffawt = salloc((size_t)NLAYERS_ * 288 * 256);
  short* gatet = salloc((size_t)NLAYERS_ * 512 * 512);
  short* ff1t  = salloc((size_t)NLAYERS_ * 1024 * 256);
  short* ff2t  = salloc((size_t)NLAYERS_ * 256 * 1024);
  short* bb1t  = salloc((size_t)NLAYERS_ * 256 * 256);
  short* bb2t  = salloc((size_t)NLAYERS_ * 256 * 256);
  short* bb3t  = salloc((size_t)NLAYERS_ * 132 * 256);
  short* pb1t  = salloc((size_t)256 * 256);
  short* pb2t  = salloc((size_t)256 * 256);
  short* pb3t  = salloc((size_t)4 * 256);
  short* sct   = salloc((size_t)80 * 256);
  size_t base_bytes = woff * sizeof(float) + soff * sizeof(short);
  if (ws_size < base_bytes) return;
  const size_t memn = (size_t)B_ * STOT_ * 256;
  bool bf16mem = (ws_size >= base_bytes + memn * sizeof(short));
  short* membf = sws + soff;

  short* qkv = (short*)U;

  float* c_prev = corners0; float* c_cur = corners1;
  float* ref_cur = refA;    float* ref_nxt = refB;

  // ---- weight prep: single dispatch ----
  WJobs P; int nb = 0; int nj = 0;
  auto addj = [&](const float* s, short* d2, int K, int N, int L, int ostr) {
    P.j[nj].src = s; P.j[nj].dst = d2; P.j[nj].K = K; P.j[nj].N = N;
    P.j[nj].tk = (K + 31) / 32; P.j[nj].tn = (N + 31) / 32;
    P.j[nj].L = L; P.j[nj].ostride = ostr; P.j[nj].blk0 = nb; P.j[nj].pad = 0;
    nb += P.j[nj].tk * P.j[nj].tn * L; ++nj;
  };
  addj(qp_w2, qp2t, 512, 256, 1, 512 * 256);
  addj(sa_qw, sqkvt,               256, 256, NLAYERS_, 768 * 256);
  addj(sa_kw, sqkvt + 256 * 256,   256, 256, NLAYERS_, 768 * 256);
  addj(sa_vw, sqkvt + 512 * 256,   256, 256, NLAYERS_, 768 * 256);
  addj(sa_ow, sowt, 256, 256, NLAYERS_, 256 * 256);
  addj(off_w, soffawt,             256, 192, NLAYERS_, 288 * 256);
  addj(aw_w,  soffawt + 192 * 256, 256,  96, NLAYERS_, 288 * 256);
  addj(gate_w, gatet, 512, 512, NLAYERS_, 512 * 512);
  addj(ff1_w, ff1t, 256, 1024, NLAYERS_, 1024 * 256);
  addj(ff2_w, ff2t, 1024, 256, NLAYERS_, 256 * 1024);
  addj(bb_w1, bb1t, 256, 256, NLAYERS_, 256 * 256);
  addj(bb_w2, bb2t, 256, 256, NLAYERS_, 256 * 256);
  addj(bb_w3, bb3t, 256, 132, NLAYERS_, 132 * 256);
  addj(pb_w1, pb1t, 256, 256, 1, 256 * 256);
  addj(pb_w2, pb2t, 256, 256, 1, 256 * 256);
  addj(pb_w3, pb3t, 256, 4, 1, 4 * 256);
  addj(sc_w + (size_t)5 * D_ * NC_, sct, 256, 80, 1, 80 * 256);
  P.njobs = nj;
  wconv_all<<<dim3(nb), 256, 0, stream>>>(P);
  if (bf16mem)
    memconv_kernel<<<dim3(B_ * STOT_ / 4), 256, 0, stream>>>(memory, membf);

  misc_init<<<egrid(R_ * 64), 256, 0, stream>>>(target, ref_unact,
      sa_qb, sa_kb, sa_vb, off_b, aw_b,
      output, outbf, out_prev, c_prev, ref_cur, qkvb, offawb);

  // layer-0 qp+qkv
  qp_qkv<<<dim3(150), 512, 0, stream>>>(ref_cur, qp_w1, qp_b1, qp2t, qp_b2,
                                        output, outbf, sqkvt, qkvb, qp, qkv);

  const void* memarg = bf16mem ? (const void*)membf : (const void*)memory;

  for (int i = 0; i < NLAYERS_; ++i) {
    attn3_kernel<<<dim3(B_ * NH_ * 2), 256, 0, stream>>>(qkv, tbf);
    int inx = (i < NLAYERS_ - 1) ? i + 1 : i;
    tail_fused<<<dim3(150), 512, 0, stream>>>(
        tbf,
        sowt + (size_t)i * 65536, sa_ob + (size_t)i * D_,
        n1_g + (size_t)i * D_, n1_b + (size_t)i * D_, qp,
        soffawt + (size_t)i * 288 * 256, offawb + (size_t)i * 288,
        memarg, ref_cur,
        gatet + (size_t)i * 262144, gate_b + (size_t)i * 512,
        gn_g + (size_t)i * D_, gn_b + (size_t)i * D_,
        ff1t + (size_t)i * 262144, ff1_b + (size_t)i * FF_,
        ff2t + (size_t)i * 262144, ff2_b + (size_t)i * D_,
        n3_g + (size_t)i * D_, n3_b + (size_t)i * D_,
        out_prev, output, outbf,
        bb1t + (size_t)i * 65536, bb_b1 + (size_t)i * D_,
        bb2t + (size_t)i * 65536, bb_b2 + (size_t)i * D_,
        bb3t + (size_t)i * 33792, bb_b3 + (size_t)i * 4 * NBIN_,
        c_prev, c_cur, ref_init, ref_nxt,
        pb1t, pb_b1, pb2t, pb_b2, pb3t, pb_b3,
        sct, sc_b + (size_t)5 * NC_,
        lqe_w1 + (size_t)5 * 20 * 64, lqe_b1 + (size_t)5 * 64,
        lqe_w2 + (size_t)5 * 64, lqe_b2 + (size_t)5, out,
        qp_w1, qp_b1, qp2t, qp_b2,
        sqkvt + (size_t)inx * 768 * 256, qkvb + (size_t)inx * 768,
        qp, qkv,
        (i == 0) ? 1 : 0, (i == NLAYERS_ - 1) ? 1 : 0, bf16mem ? 1 : 0);
    std::swap(c_prev, c_cur);
    std::swap(ref_cur, ref_nxt);
  }
}

// Round 6
// 1566.135 us; speedup vs baseline: 1.1772x; 1.1772x over previous
//
#include <hip/hip_runtime.h>
#include <cstddef>
#include <cmath>
#include <utility>

#define B_ 16
#define LQ_ 300
#define D_ 256
#define NH_ 8
#define HD_ 32
#define FF_ 1024
#define NBIN_ 33
#define NC_ 80
#define SUMP_ 12
#define STOT_ 8400
#define R_ (B_*LQ_)        // 4800
#define NLAYERS_ 6

typedef short bf16x8 __attribute__((ext_vector_type(8)));
typedef float f32x4  __attribute__((ext_vector_type(4)));

static __device__ __forceinline__ short f2bf(float x) {
  union { float f; unsigned u; } v; v.f = x;
  unsigned r = v.u + 0x7fffu + ((v.u >> 16) & 1u);   // RNE
  return (short)(r >> 16);
}
static __device__ __forceinline__ float bf2f(short s) {
  union { unsigned u; float f; } v; v.u = ((unsigned)(unsigned short)s) << 16; return v.f;
}

// ---------------------------------------------------------------------------
// One-dispatch weight convert+transpose for ALL weights.
// ---------------------------------------------------------------------------
struct WJob { const float* src; short* dst; int K, N, tk, tn, L, ostride, blk0, pad; };
struct WJobs { WJob j[17]; int njobs; };

__launch_bounds__(256)
__global__ void wconv_all(WJobs P) {
  __shared__ float t[32][33];
  const int b = blockIdx.x;
  int ji = 0;
  for (int k = 1; k < P.njobs; ++k) ji = (b >= P.j[k].blk0) ? k : ji;
  const float* src = P.j[ji].src;
  short* dst = P.j[ji].dst;
  const int K = P.j[ji].K, N = P.j[ji].N, tk = P.j[ji].tk;
  int rel = b - P.j[ji].blk0;
  int per = tk * P.j[ji].tn;
  int l = rel / per; int r2 = rel - l * per;
  int tki = r2 % tk, tni = r2 / tk;
  const float* Wl = src + (size_t)l * K * N;
  short* Wtl = dst + (size_t)l * (size_t)P.j[ji].ostride;
  int k0 = tki * 32, n0 = tni * 32;
  int tr = threadIdx.x >> 5, tc = threadIdx.x & 31;
  #pragma unroll
  for (int i = 0; i < 4; ++i) {
    int k = k0 + tr + i * 8, n = n0 + tc;
    t[tr + i * 8][tc] = (k < K && n < N) ? Wl[(size_t)k * N + n] : 0.f;
  }
  __syncthreads();
  #pragma unroll
  for (int i = 0; i < 4; ++i) {
    int n = n0 + tr + i * 8, k = k0 + tc;
    if (n < N && k < K) Wtl[(size_t)n * K + k] = f2bf(t[tc][tr + i * 8]);
  }
}

// memory fp32 [B,S,256] -> bf16 head-major [B,NH,S,32]
__launch_bounds__(256)
__global__ void memconv_kernel(const float* __restrict__ mem, short* __restrict__ mb) {
  int gs = blockIdx.x * 4 + (threadIdx.x >> 6);
  int c  = (threadIdx.x & 63) * 4;
  int b = gs / STOT_, s = gs - b * STOT_;
  float4 v = *(const float4*)(mem + (size_t)gs * 256 + c);
  int h = c >> 5, cc = c & 31;
  short4 o; o.x = f2bf(v.x); o.y = f2bf(v.y); o.z = f2bf(v.z); o.w = f2bf(v.w);
  *(short4*)(mb + (((size_t)(b * 8 + h) * STOT_ + s) * 32) + cc) = o;
}

// ---------------------------------------------------------------------------
// One-dispatch init.
// ---------------------------------------------------------------------------
__launch_bounds__(256)
__global__ void misc_init(const float* __restrict__ target, const float* __restrict__ refu,
                          const float* __restrict__ qb, const float* __restrict__ kb,
                          const float* __restrict__ vb, const float* __restrict__ ob,
                          const float* __restrict__ ab,
                          float* __restrict__ output, short* __restrict__ outbf,
                          float* __restrict__ out_prev, float* __restrict__ cprev,
                          float* __restrict__ refcur, float* __restrict__ qkvb,
                          float* __restrict__ offawb) {
  int i = blockIdx.x * 256 + threadIdx.x;
  float4 z; z.x = 0.f; z.y = 0.f; z.z = 0.f; z.w = 0.f;
  if (i < R_ * 64) {
    float4 v = ((const float4*)target)[i];
    ((float4*)output)[i] = v;
    short4 s; s.x = f2bf(v.x); s.y = f2bf(v.y); s.z = f2bf(v.z); s.w = f2bf(v.w);
    ((short4*)outbf)[i] = s;
    ((float4*)out_prev)[i] = z;
  }
  if (i < R_ * 33) ((float4*)cprev)[i] = z;
  if (i < R_) {
    float4 r = ((const float4*)refu)[i];
    float4 o;
    o.x = 1.f / (1.f + __expf(-r.x)); o.y = 1.f / (1.f + __expf(-r.y));
    o.z = 1.f / (1.f + __expf(-r.z)); o.w = 1.f / (1.f + __expf(-r.w));
    ((float4*)refcur)[i] = o;
  }
  if (i < NLAYERS_ * 768) {
    int l = i / 768, c = i % 768;
    qkvb[i] = (c < 256) ? qb[l * 256 + c] : (c < 512) ? kb[l * 256 + c - 256]
                        : vb[l * 256 + c - 512];
  }
  if (i < NLAYERS_ * 288) {
    int l = i / 288, c = i % 288;
    offawb[i] = (c < 192) ? ob[l * 192 + c] : ab[l * 96 + c - 192];
  }
}

// ---------------------------------------------------------------------------
// Fused qp MLP + qkv GEMM. Block = 32 rows x 8 waves, 2 row-tiles/wave.
// Grid 150.
// ---------------------------------------------------------------------------
__launch_bounds__(512)
__global__ void qp_qkv(const float* __restrict__ ref, const float* __restrict__ W1,
                       const float* __restrict__ b1, const short* __restrict__ W2t,
                       const float* __restrict__ b2, const float* __restrict__ output,
                       const short* __restrict__ outbf,
                       const short* __restrict__ Qt, const float* __restrict__ qkvbias,
                       float* __restrict__ qpout, short* __restrict__ qkvout) {
  __shared__ short sh[32 * 520];
  __shared__ short oqs[32][264];
  const int m0 = blockIdx.x * 32;
  const int tid = threadIdx.x;
  for (int i = tid; i < 32 * 512; i += 512) {
    int r = i >> 9, n = i & 511;
    float4 rv = *(const float4*)(ref + (size_t)(m0 + r) * 4);
    float v = b1[n] + rv.x * W1[n] + rv.y * W1[512 + n] + rv.z * W1[1024 + n]
            + rv.w * W1[1536 + n];
    v = v / (1.f + __expf(-v));
    sh[r * 520 + n] = f2bf(v);
  }
  __syncthreads();
  const int wid = tid >> 6, lane = tid & 63;
  const int lr = lane & 15, lq = lane >> 4;
  {
    // qp GEMM: N=256, 8 waves x 32 cols, 2 row tiles
    f32x4 acc[2][2];
    #pragma unroll
    for (int ti = 0; ti < 2; ++ti)
      #pragma unroll
      for (int t = 0; t < 2; ++t) acc[ti][t] = (f32x4){0.f, 0.f, 0.f, 0.f};
    #pragma unroll 8
    for (int k0 = 0; k0 < 512; k0 += 32) {
      bf16x8 a0 = *(const bf16x8*)&sh[lr * 520 + k0 + lq * 8];
      bf16x8 a1 = *(const bf16x8*)&sh[(16 + lr) * 520 + k0 + lq * 8];
      #pragma unroll
      for (int t = 0; t < 2; ++t) {
        bf16x8 w = *(const bf16x8*)(W2t + (size_t)(wid * 32 + t * 16 + lr) * 512 + k0 + lq * 8);
        acc[0][t] = __builtin_amdgcn_mfma_f32_16x16x32_bf16(a0, w, acc[0][t], 0, 0, 0);
        acc[1][t] = __builtin_amdgcn_mfma_f32_16x16x32_bf16(a1, w, acc[1][t], 0, 0, 0);
      }
    }
    #pragma unroll
    for (int t = 0; t < 2; ++t) {
      int col = wid * 32 + t * 16 + lr;
      float bv = b2[col];
      #pragma unroll
      for (int ti = 0; ti < 2; ++ti)
        #pragma unroll
        for (int rr = 0; rr < 4; ++rr) {
          int rl = ti * 16 + lq * 4 + rr;
          size_t idx = (size_t)(m0 + rl) * 256 + col;
          float v = fminf(fmaxf(acc[ti][t][rr] + bv, -10.f), 10.f);
          qpout[idx] = v;
          oqs[rl][col] = f2bf(v + output[idx]);
        }
    }
  }
  __syncthreads();
  {
    // qkv GEMM: N=768, 8 waves x 96 cols (6 tiles), 2 row tiles
    f32x4 acc[2][6];
    #pragma unroll
    for (int ti = 0; ti < 2; ++ti)
      #pragma unroll
      for (int t = 0; t < 6; ++t) acc[ti][t] = (f32x4){0.f, 0.f, 0.f, 0.f};
    const int cbase = wid * 96;
    const short* obp0 = outbf + (size_t)(m0 + lr) * 256;
    const short* obp1 = outbf + (size_t)(m0 + 16 + lr) * 256;
    #pragma unroll 4
    for (int k0 = 0; k0 < 256; k0 += 32) {
      bf16x8 aq0 = *(const bf16x8*)&oqs[lr][k0 + lq * 8];
      bf16x8 aq1 = *(const bf16x8*)&oqs[16 + lr][k0 + lq * 8];
      bf16x8 ab0 = *(const bf16x8*)(obp0 + k0 + lq * 8);
      bf16x8 ab1 = *(const bf16x8*)(obp1 + k0 + lq * 8);
      #pragma unroll
      for (int t = 0; t < 6; ++t) {
        bf16x8 w = *(const bf16x8*)(Qt + (size_t)(cbase + t * 16 + lr) * 256 + k0 + lq * 8);
        bool useoq = (cbase + t * 16) < 512;
        acc[0][t] = __builtin_amdgcn_mfma_f32_16x16x32_bf16(useoq ? aq0 : ab0, w, acc[0][t], 0, 0, 0);
        acc[1][t] = __builtin_amdgcn_mfma_f32_16x16x32_bf16(useoq ? aq1 : ab1, w, acc[1][t], 0, 0, 0);
      }
    }
    #pragma unroll
    for (int t = 0; t < 6; ++t) {
      int colt = cbase + t * 16 + lr;
      float bv = qkvbias[colt];
      #pragma unroll
      for (int ti = 0; ti < 2; ++ti)
        #pragma unroll
        for (int rr = 0; rr < 4; ++rr)
          qkvout[(size_t)(m0 + ti * 16 + lq * 4 + rr) * 768 + colt] = f2bf(acc[ti][t][rr] + bv);
    }
  }
}

// ---------------------------------------------------------------------------
// Fused sow GEMM + LN + offset/attn-weight GEMM. 32 rows, 2 row-tiles/wave.
// ---------------------------------------------------------------------------
__launch_bounds__(512)
__global__ void sow_ln_off(const short* __restrict__ A, const short* __restrict__ Wt,
                           const float* __restrict__ bias, const float* __restrict__ resid,
                           const float* __restrict__ gamma, const float* __restrict__ beta,
                           const float* __restrict__ qp,
                           const short* __restrict__ OWt, const float* __restrict__ ob,
                           float* __restrict__ outf, short* __restrict__ outbf,
                           float* __restrict__ offout) {
  __shared__ float ssum[32][8];
  __shared__ float ssq[32][8];
  __shared__ short oqs[32][264];
  const int m0 = blockIdx.x * 32;
  const int tid = threadIdx.x, wid = tid >> 6, lane = tid & 63;
  const int lr = lane & 15, lq = lane >> 4;
  const int cw = wid * 32;
  f32x4 acc[2][2];
  #pragma unroll
  for (int ti = 0; ti < 2; ++ti)
    #pragma unroll
    for (int t = 0; t < 2; ++t) acc[ti][t] = (f32x4){0.f, 0.f, 0.f, 0.f};
  #pragma unroll
  for (int k0 = 0; k0 < 256; k0 += 32) {
    bf16x8 a0 = *(const bf16x8*)(A + (size_t)(m0 + lr) * 256 + k0 + lq * 8);
    bf16x8 a1 = *(const bf16x8*)(A + (size_t)(m0 + 16 + lr) * 256 + k0 + lq * 8);
    #pragma unroll
    for (int t = 0; t < 2; ++t) {
      bf16x8 w = *(const bf16x8*)(Wt + (size_t)(cw + t * 16 + lr) * 256 + k0 + lq * 8);
      acc[0][t] = __builtin_amdgcn_mfma_f32_16x16x32_bf16(a0, w, acc[0][t], 0, 0, 0);
      acc[1][t] = __builtin_amdgcn_mfma_f32_16x16x32_bf16(a1, w, acc[1][t], 0, 0, 0);
    }
  }
  float s[2][4], q[2][4];
  #pragma unroll
  for (int ti = 0; ti < 2; ++ti)
    #pragma unroll
    for (int rr = 0; rr < 4; ++rr) { s[ti][rr] = 0.f; q[ti][rr] = 0.f; }
  #pragma unroll
  for (int t = 0; t < 2; ++t) {
    int col = cw + t * 16 + lr;
    float bv = bias[col];
    #pragma unroll
    for (int ti = 0; ti < 2; ++ti)
      #pragma unroll
      for (int rr = 0; rr < 4; ++rr) {
        int rowg = m0 + ti * 16 + lq * 4 + rr;
        float x = acc[ti][t][rr] + bv + resid[(size_t)rowg * 256 + col];
        acc[ti][t][rr] = x;
        s[ti][rr] += x; q[ti][rr] += x * x;
      }
  }
  #pragma unroll
  for (int m = 1; m < 16; m <<= 1)
    #pragma unroll
    for (int ti = 0; ti < 2; ++ti)
      #pragma unroll
      for (int rr = 0; rr < 4; ++rr) {
        s[ti][rr] += __shfl_xor(s[ti][rr], m);
        q[ti][rr] += __shfl_xor(q[ti][rr], m);
      }
  if (lr == 0)
    #pragma unroll
    for (int ti = 0; ti < 2; ++ti)
      #pragma unroll
      for (int rr = 0; rr < 4; ++rr) {
        ssum[ti * 16 + lq * 4 + rr][wid] = s[ti][rr];
        ssq[ti * 16 + lq * 4 + rr][wid] = q[ti][rr];
      }
  __syncthreads();
  float mu[2][4], rs[2][4];
  #pragma unroll
  for (int ti = 0; ti < 2; ++ti)
    #pragma unroll
    for (int rr = 0; rr < 4; ++rr) {
      int rl = ti * 16 + lq * 4 + rr;
      float sm = 0.f, sq = 0.f;
      #pragma unroll
      for (int w8 = 0; w8 < 8; ++w8) { sm += ssum[rl][w8]; sq += ssq[rl][w8]; }
      float m_ = sm * (1.f / 256.f);
      float var = sq * (1.f / 256.f) - m_ * m_;
      mu[ti][rr] = m_; rs[ti][rr] = rsqrtf(var + 1e-5f);
    }
  #pragma unroll
  for (int t = 0; t < 2; ++t) {
    int col = cw + t * 16 + lr;
    float g = gamma[col], be = beta[col];
    #pragma unroll
    for (int ti = 0; ti < 2; ++ti)
      #pragma unroll
      for (int rr = 0; rr < 4; ++rr) {
        int rl = ti * 16 + lq * 4 + rr;
        size_t idx = (size_t)(m0 + rl) * 256 + col;
        float v = (acc[ti][t][rr] - mu[ti][rr]) * rs[ti][rr] * g + be;
        outf[idx] = v;
        outbf[idx] = f2bf(v);
        oqs[rl][col] = f2bf(v + qp[idx]);
      }
  }
  __syncthreads();
  // ---- off GEMM: 288 cols = 18 tiles over 8 waves, 2 row tiles ----
  f32x4 oacc[2][3];
  #pragma unroll
  for (int ti = 0; ti < 2; ++ti)
    #pragma unroll
    for (int j = 0; j < 3; ++j) oacc[ti][j] = (f32x4){0.f, 0.f, 0.f, 0.f};
  #pragma unroll 4
  for (int k0 = 0; k0 < 256; k0 += 32) {
    bf16x8 a0 = *(const bf16x8*)&oqs[lr][k0 + lq * 8];
    bf16x8 a1 = *(const bf16x8*)&oqs[16 + lr][k0 + lq * 8];
    #pragma unroll
    for (int j = 0; j < 3; ++j) {
      int tile = wid + j * 8;
      int trow = (tile < 18) ? tile * 16 + lr : 0;
      bf16x8 w = *(const bf16x8*)(OWt + (size_t)trow * 256 + k0 + lq * 8);
      oacc[0][j] = __builtin_amdgcn_mfma_f32_16x16x32_bf16(a0, w, oacc[0][j], 0, 0, 0);
      oacc[1][j] = __builtin_amdgcn_mfma_f32_16x16x32_bf16(a1, w, oacc[1][j], 0, 0, 0);
    }
  }
  #pragma unroll
  for (int j = 0; j < 3; ++j) {
    int tile = wid + j * 8;
    if (tile >= 18) continue;
    int col = tile * 16 + lr;
    float bv = ob[col];
    #pragma unroll
    for (int ti = 0; ti < 2; ++ti)
      #pragma unroll
      for (int rr = 0; rr < 4; ++rr)
        offout[(size_t)(m0 + ti * 16 + lq * 4 + rr) * 288 + col] = oacc[ti][j][rr] + bv;
  }
}

// ---------------------------------------------------------------------------
// Fused FFN. 32 rows, 2 row-tiles/wave. Optional scores GEMM.
// ---------------------------------------------------------------------------
template<int SCORES>
__launch_bounds__(512)
__global__ void ffn_ln(const short* __restrict__ A, const short* __restrict__ W1t,
                       const float* __restrict__ b1, const short* __restrict__ W2t,
                       const float* __restrict__ b2, const float* __restrict__ resid,
                       const float* __restrict__ gamma, const float* __restrict__ beta,
                       float* __restrict__ prev, float* __restrict__ outf,
                       short* __restrict__ outbf, short* __restrict__ oqbf,
                       const short* __restrict__ SCt, const float* __restrict__ scb,
                       float* __restrict__ scoresOut) {
  __shared__ short hid[32][1032];
  __shared__ float ssum[32][8];
  __shared__ float ssq[32][8];
  const int m0 = blockIdx.x * 32;
  const int tid = threadIdx.x, wid = tid >> 6, lane = tid & 63;
  const int lr = lane & 15, lq = lane >> 4;
  // ---- P0: hid = relu(A@W1t + b1), 8 waves x 128 cols, 2 row tiles ----
  {
    f32x4 acc[2][8];
    #pragma unroll
    for (int ti = 0; ti < 2; ++ti)
      #pragma unroll
      for (int t = 0; t < 8; ++t) acc[ti][t] = (f32x4){0.f, 0.f, 0.f, 0.f};
    #pragma unroll 4
    for (int k0 = 0; k0 < 256; k0 += 32) {
      bf16x8 a0 = *(const bf16x8*)(A + (size_t)(m0 + lr) * 256 + k0 + lq * 8);
      bf16x8 a1 = *(const bf16x8*)(A + (size_t)(m0 + 16 + lr) * 256 + k0 + lq * 8);
      #pragma unroll
      for (int t = 0; t < 8; ++t) {
        bf16x8 w = *(const bf16x8*)(W1t + (size_t)(wid * 128 + t * 16 + lr) * 256 + k0 + lq * 8);
        acc[0][t] = __builtin_amdgcn_mfma_f32_16x16x32_bf16(a0, w, acc[0][t], 0, 0, 0);
        acc[1][t] = __builtin_amdgcn_mfma_f32_16x16x32_bf16(a1, w, acc[1][t], 0, 0, 0);
      }
    }
    #pragma unroll
    for (int t = 0; t < 8; ++t) {
      int col = wid * 128 + t * 16 + lr;
      float bv = b1[col];
      #pragma unroll
      for (int ti = 0; ti < 2; ++ti)
        #pragma unroll
        for (int rr = 0; rr < 4; ++rr)
          hid[ti * 16 + lq * 4 + rr][col] = f2bf(fmaxf(acc[ti][t][rr] + bv, 0.f));
    }
  }
  __syncthreads();
  // ---- P1: out = hid@W2t + b2 + resid, clip, LN ----
  const int cw = wid * 32;
  f32x4 acc[2][2];
  #pragma unroll
  for (int ti = 0; ti < 2; ++ti)
    #pragma unroll
    for (int t = 0; t < 2; ++t) acc[ti][t] = (f32x4){0.f, 0.f, 0.f, 0.f};
  #pragma unroll 8
  for (int k0 = 0; k0 < 1024; k0 += 32) {
    bf16x8 a0 = *(const bf16x8*)&hid[lr][k0 + lq * 8];
    bf16x8 a1 = *(const bf16x8*)&hid[16 + lr][k0 + lq * 8];
    #pragma unroll
    for (int t = 0; t < 2; ++t) {
      bf16x8 w = *(const bf16x8*)(W2t + (size_t)(cw + t * 16 + lr) * 1024 + k0 + lq * 8);
      acc[0][t] = __builtin_amdgcn_mfma_f32_16x16x32_bf16(a0, w, acc[0][t], 0, 0, 0);
      acc[1][t] = __builtin_amdgcn_mfma_f32_16x16x32_bf16(a1, w, acc[1][t], 0, 0, 0);
    }
  }
  float s[2][4], q[2][4];
  #pragma unroll
  for (int ti = 0; ti < 2; ++ti)
    #pragma unroll
    for (int rr = 0; rr < 4; ++rr) { s[ti][rr] = 0.f; q[ti][rr] = 0.f; }
  #pragma unroll
  for (int t = 0; t < 2; ++t) {
    int col = cw + t * 16 + lr;
    float bv = b2[col];
    #pragma unroll
    for (int ti = 0; ti < 2; ++ti)
      #pragma unroll
      for (int rr = 0; rr < 4; ++rr) {
        int rowg = m0 + ti * 16 + lq * 4 + rr;
        float x = acc[ti][t][rr] + bv + resid[(size_t)rowg * 256 + col];
        x = fminf(fmaxf(x, -65504.f), 65504.f);
        acc[ti][t][rr] = x;
        s[ti][rr] += x; q[ti][rr] += x * x;
      }
  }
  #pragma unroll
  for (int m = 1; m < 16; m <<= 1)
    #pragma unroll
    for (int ti = 0; ti < 2; ++ti)
      #pragma unroll
      for (int rr = 0; rr < 4; ++rr) {
        s[ti][rr] += __shfl_xor(s[ti][rr], m);
        q[ti][rr] += __shfl_xor(q[ti][rr], m);
      }
  if (lr == 0)
    #pragma unroll
    for (int ti = 0; ti < 2; ++ti)
      #pragma unroll
      for (int rr = 0; rr < 4; ++rr) {
        ssum[ti * 16 + lq * 4 + rr][wid] = s[ti][rr];
        ssq[ti * 16 + lq * 4 + rr][wid] = q[ti][rr];
      }
  __syncthreads();
  float mu[2][4], rs[2][4];
  #pragma unroll
  for (int ti = 0; ti < 2; ++ti)
    #pragma unroll
    for (int rr = 0; rr < 4; ++rr) {
      int rl = ti * 16 + lq * 4 + rr;
      float sm = 0.f, sq = 0.f;
      #pragma unroll
      for (int w8 = 0; w8 < 8; ++w8) { sm += ssum[rl][w8]; sq += ssq[rl][w8]; }
      float m_ = sm * (1.f / 256.f);
      float var = sq * (1.f / 256.f) - m_ * m_;
      mu[ti][rr] = m_; rs[ti][rr] = rsqrtf(var + 1e-5f);
    }
  #pragma unroll
  for (int t = 0; t < 2; ++t) {
    int col = cw + t * 16 + lr;
    float g = gamma[col], be = beta[col];
    #pragma unroll
    for (int ti = 0; ti < 2; ++ti)
      #pragma unroll
      for (int rr = 0; rr < 4; ++rr) {
        int rl = ti * 16 + lq * 4 + rr;
        size_t idx = (size_t)(m0 + rl) * 256 + col;
        float v = (acc[ti][t][rr] - mu[ti][rr]) * rs[ti][rr] * g + be;
        outf[idx] = v;
        short vb = f2bf(v);
        outbf[idx] = vb;
        float po = prev[idx];
        oqbf[idx] = f2bf(v + po);
        prev[idx] = v;
        if (SCORES) hid[rl][col] = vb;
      }
  }
  if (SCORES) {
    __syncthreads();
    // scores: N=80 = 5 tiles; waves 0..4, 2 row tiles each
    f32x4 sacc[2];
    sacc[0] = (f32x4){0.f, 0.f, 0.f, 0.f};
    sacc[1] = (f32x4){0.f, 0.f, 0.f, 0.f};
    int trow = (wid < 5) ? wid * 16 + lr : 0;
    #pragma unroll 4
    for (int k0 = 0; k0 < 256; k0 += 32) {
      bf16x8 a0 = *(const bf16x8*)&hid[lr][k0 + lq * 8];
      bf16x8 a1 = *(const bf16x8*)&hid[16 + lr][k0 + lq * 8];
      bf16x8 w = *(const bf16x8*)(SCt + (size_t)trow * 256 + k0 + lq * 8);
      sacc[0] = __builtin_amdgcn_mfma_f32_16x16x32_bf16(a0, w, sacc[0], 0, 0, 0);
      sacc[1] = __builtin_amdgcn_mfma_f32_16x16x32_bf16(a1, w, sacc[1], 0, 0, 0);
    }
    if (wid < 5) {
      int col = wid * 16 + lr;
      float bv = scb[col];
      #pragma unroll
      for (int ti = 0; ti < 2; ++ti)
        #pragma unroll
        for (int rr = 0; rr < 4; ++rr)
          scoresOut[(size_t)(m0 + ti * 16 + lq * 4 + rr) * 80 + col] = sacc[ti][rr] + bv;
    }
  }
}

// ---------------------------------------------------------------------------
// Fused FDR chain (32 rows, 2 row-tiles/wave) + optional LQE tail.
// ---------------------------------------------------------------------------
template<int LQE>
__launch_bounds__(512)
__global__ void fdr_kernel(const short* __restrict__ A,
                           const short* __restrict__ W1t, const float* __restrict__ b1,
                           const short* __restrict__ W2t, const float* __restrict__ b2,
                           const short* __restrict__ W3t, const float* __restrict__ b3,
                           const float* __restrict__ cprev, const float* __restrict__ refi,
                           float* __restrict__ ccur, float* __restrict__ refn,
                           const float* __restrict__ scores, const float* __restrict__ lw1,
                           const float* __restrict__ lb1, const float* __restrict__ lw2,
                           const float* __restrict__ lb2, float* __restrict__ outp) {
  __shared__ short h1[32][264];
  __shared__ short h2[32][264];
  __shared__ float cor[32][132];
  __shared__ float dstl[32][4];
  __shared__ float projs[33];
  __shared__ float statl[32][20];
  __shared__ float interb[32][4];
  __shared__ float lqes[32];
  const int m0 = blockIdx.x * 32;
  const int tid = threadIdx.x, wid = tid >> 6, lane = tid & 63;
  const int lr = lane & 15, lq = lane >> 4;
  if (tid < 33) {
    float v;
    if (tid == 0) v = -4.f;
    else if (tid == 32) v = 4.f;
    else if (tid == 16) v = 0.f;
    else if (tid < 16) v = 1.f - powf(3.f, (float)(16 - tid) * (1.f / 15.f));
    else v = powf(3.f, (float)(tid - 16) * (1.f / 15.f)) - 1.f;
    projs[tid] = v;
  }
  // ---- P0: h1 = silu(A@W1t + b1) ----
  {
    f32x4 acc[2][2];
    #pragma unroll
    for (int ti = 0; ti < 2; ++ti)
      #pragma unroll
      for (int t = 0; t < 2; ++t) acc[ti][t] = (f32x4){0.f, 0.f, 0.f, 0.f};
    #pragma unroll
    for (int k0 = 0; k0 < 256; k0 += 32) {
      bf16x8 a0 = *(const bf16x8*)(A + (size_t)(m0 + lr) * 256 + k0 + lq * 8);
      bf16x8 a1 = *(const bf16x8*)(A + (size_t)(m0 + 16 + lr) * 256 + k0 + lq * 8);
      #pragma unroll
      for (int t = 0; t < 2; ++t) {
        bf16x8 w = *(const bf16x8*)(W1t + (size_t)(wid * 32 + t * 16 + lr) * 256 + k0 + lq * 8);
        acc[0][t] = __builtin_amdgcn_mfma_f32_16x16x32_bf16(a0, w, acc[0][t], 0, 0, 0);
        acc[1][t] = __builtin_amdgcn_mfma_f32_16x16x32_bf16(a1, w, acc[1][t], 0, 0, 0);
      }
    }
    #pragma unroll
    for (int t = 0; t < 2; ++t) {
      int col = wid * 32 + t * 16 + lr;
      float bv = b1[col];
      #pragma unroll
      for (int ti = 0; ti < 2; ++ti)
        #pragma unroll
        for (int rr = 0; rr < 4; ++rr) {
          float v = acc[ti][t][rr] + bv;
          v = v / (1.f + __expf(-v));
          h1[ti * 16 + lq * 4 + rr][col] = f2bf(v);
        }
    }
  }
  __syncthreads();
  // ---- P1: h2 = silu(h1@W2t + b2) ----
  {
    f32x4 acc[2][2];
    #pragma unroll
    for (int ti = 0; ti < 2; ++ti)
      #pragma unroll
      for (int t = 0; t < 2; ++t) acc[ti][t] = (f32x4){0.f, 0.f, 0.f, 0.f};
    #pragma unroll
    for (int k0 = 0; k0 < 256; k0 += 32) {
      bf16x8 a0 = *(const bf16x8*)&h1[lr][k0 + lq * 8];
      bf16x8 a1 = *(const bf16x8*)&h1[16 + lr][k0 + lq * 8];
      #pragma unroll
      for (int t = 0; t < 2; ++t) {
        bf16x8 w = *(const bf16x8*)(W2t + (size_t)(wid * 32 + t * 16 + lr) * 256 + k0 + lq * 8);
        acc[0][t] = __builtin_amdgcn_mfma_f32_16x16x32_bf16(a0, w, acc[0][t], 0, 0, 0);
        acc[1][t] = __builtin_amdgcn_mfma_f32_16x16x32_bf16(a1, w, acc[1][t], 0, 0, 0);
      }
    }
    #pragma unroll
    for (int t = 0; t < 2; ++t) {
      int col = wid * 32 + t * 16 + lr;
      float bv = b2[col];
      #pragma unroll
      for (int ti = 0; ti < 2; ++ti)
        #pragma unroll
        for (int rr = 0; rr < 4; ++rr) {
          float v = acc[ti][t][rr] + bv;
          v = v / (1.f + __expf(-v));
          h2[ti * 16 + lq * 4 + rr][col] = f2bf(v);
        }
    }
  }
  __syncthreads();
  // ---- P2: corners = h2@W3t + b3 + c_prev (N=132, 9 tiles over 8 waves) ----
  {
    f32x4 acc[2][2];
    int col[2], wr[2];
    #pragma unroll
    for (int j = 0; j < 2; ++j) {
      acc[0][j] = (f32x4){0.f, 0.f, 0.f, 0.f};
      acc[1][j] = (f32x4){0.f, 0.f, 0.f, 0.f};
      col[j] = (wid + j * 8) * 16 + lr;
      wr[j] = (col[j] < 132) ? col[j] : 0;
    }
    #pragma unroll
    for (int k0 = 0; k0 < 256; k0 += 32) {
      bf16x8 a0 = *(const bf16x8*)&h2[lr][k0 + lq * 8];
      bf16x8 a1 = *(const bf16x8*)&h2[16 + lr][k0 + lq * 8];
      #pragma unroll
      for (int j = 0; j < 2; ++j) {
        bf16x8 w = *(const bf16x8*)(W3t + (size_t)wr[j] * 256 + k0 + lq * 8);
        acc[0][j] = __builtin_amdgcn_mfma_f32_16x16x32_bf16(a0, w, acc[0][j], 0, 0, 0);
        acc[1][j] = __builtin_amdgcn_mfma_f32_16x16x32_bf16(a1, w, acc[1][j], 0, 0, 0);
      }
    }
    #pragma unroll
    for (int j = 0; j < 2; ++j) {
      if (col[j] >= 132) continue;
      float bv = b3[col[j]];
      #pragma unroll
      for (int ti = 0; ti < 2; ++ti)
        #pragma unroll
        for (int rr = 0; rr < 4; ++rr) {
          int rl = ti * 16 + lq * 4 + rr, g = m0 + rl;
          float v = acc[ti][j][rr] + bv + cprev[(size_t)g * 132 + col[j]];
          ccur[(size_t)g * 132 + col[j]] = v;
          cor[rl][col[j]] = v;
        }
    }
  }
  __syncthreads();
  // ---- P3a: softmax-dot per (row, side) ----
  if (tid < 128) {
    int r = tid >> 2, sd = tid & 3;
    const float* cp = &cor[r][sd * 33];
    float m = -1e30f;
    #pragma unroll
    for (int j = 0; j < 33; ++j) m = fmaxf(m, cp[j]);
    float t0 = -1e30f, t1 = -1e30f, t2v = -1e30f, t3 = -1e30f;
    float sum = 0.f, dot = 0.f;
    #pragma unroll
    for (int j = 0; j < 33; ++j) {
      float e = __expf(cp[j] - m);
      sum += e; dot += e * projs[j];
      if (LQE) {
        if (e > t0)      { t3 = t2v; t2v = t1; t1 = t0; t0 = e; }
        else if (e > t1) { t3 = t2v; t2v = t1; t1 = e; }
        else if (e > t2v){ t3 = t2v; t2v = e; }
        else if (e > t3) { t3 = e; }
      }
    }
    dstl[r][sd] = dot / sum;
    if (LQE) {
      float inv = 1.f / sum;
      float v0 = t0 * inv, v1 = t1 * inv, v2 = t2v * inv, v3 = t3 * inv;
      statl[r][sd * 5 + 0] = v0; statl[r][sd * 5 + 1] = v1;
      statl[r][sd * 5 + 2] = v2; statl[r][sd * 5 + 3] = v3;
      statl[r][sd * 5 + 4] = (v0 + v1 + v2 + v3) * 0.25f;
    }
  }
  __syncthreads();
  // ---- P3b: distance2bbox per row ----
  if (tid < 32) {
    int g = m0 + tid;
    float px = refi[g * 4], py = refi[g * 4 + 1];
    float qw = refi[g * 4 + 2] * 0.25f, qh = refi[g * 4 + 3] * 0.25f;
    float x1 = px - (2.f + dstl[tid][0]) * qw, y1 = py - (2.f + dstl[tid][1]) * qh;
    float x2 = px + (2.f + dstl[tid][2]) * qw, y2 = py + (2.f + dstl[tid][3]) * qh;
    float4 o; o.x = (x1 + x2) * 0.5f; o.y = (y1 + y2) * 0.5f; o.z = x2 - x1; o.w = y2 - y1;
    *(float4*)(refn + (size_t)g * 4) = o;
    if (LQE) { interb[tid][0] = o.x; interb[tid][1] = o.y; interb[tid][2] = o.z; interb[tid][3] = o.w; }
  }
  if (LQE) {
    // ---- P4: per-row 20->64->1 MLP; 8 waves x 4 rows ----
    #pragma unroll
    for (int it = 0; it < 4; ++it) {
      int row = wid * 4 + it;
      float sv = lb1[lane];
      #pragma unroll
      for (int i = 0; i < 20; ++i) sv += statl[row][i] * lw1[i * 64 + lane];
      float hv = sv / (1.f + __expf(-sv));
      float v = hv * lw2[lane];
      #pragma unroll
      for (int o = 32; o; o >>= 1) v += __shfl_xor(v, o);
      if (lane == 0) lqes[row] = v + lb2[0];
    }
    __syncthreads();
    for (int idx = tid; idx < 32 * 84; idx += 512) {
      int r = idx / 84, c = idx - r * 84;
      int g = m0 + r;
      outp[(size_t)g * 84 + c] = (c < 4) ? interb[r][c]
                                         : scores[(size_t)g * 80 + (c - 4)] + lqes[r];
    }
  }
}

// ---------------------------------------------------------------------------
// Fused pre-bbox (layer 0), 32 rows, 2 row-tiles/wave.
// ---------------------------------------------------------------------------
__launch_bounds__(512)
__global__ void pb_fused(const short* __restrict__ A,
                         const short* __restrict__ W1t, const float* __restrict__ b1,
                         const short* __restrict__ W2t, const float* __restrict__ b2,
                         const short* __restrict__ W3t, const float* __restrict__ b3,
                         const float* __restrict__ refc, float* __restrict__ refinit) {
  __shared__ short h1[32][264];
  __shared__ short h2[32][264];
  const int m0 = blockIdx.x * 32;
  const int tid = threadIdx.x, wid = tid >> 6, lane = tid & 63;
  const int lr = lane & 15, lq = lane >> 4;
  {
    f32x4 acc[2][2];
    #pragma unroll
    for (int ti = 0; ti < 2; ++ti)
      #pragma unroll
      for (int t = 0; t < 2; ++t) acc[ti][t] = (f32x4){0.f, 0.f, 0.f, 0.f};
    #pragma unroll
    for (int k0 = 0; k0 < 256; k0 += 32) {
      bf16x8 a0 = *(const bf16x8*)(A + (size_t)(m0 + lr) * 256 + k0 + lq * 8);
      bf16x8 a1 = *(const bf16x8*)(A + (size_t)(m0 + 16 + lr) * 256 + k0 + lq * 8);
      #pragma unroll
      for (int t = 0; t < 2; ++t) {
        bf16x8 w = *(const bf16x8*)(W1t + (size_t)(wid * 32 + t * 16 + lr) * 256 + k0 + lq * 8);
        acc[0][t] = __builtin_amdgcn_mfma_f32_16x16x32_bf16(a0, w, acc[0][t], 0, 0, 0);
        acc[1][t] = __builtin_amdgcn_mfma_f32_16x16x32_bf16(a1, w, acc[1][t], 0, 0, 0);
      }
    }
    #pragma unroll
    for (int t = 0; t < 2; ++t) {
      int col = wid * 32 + t * 16 + lr;
      float bv = b1[col];
      #pragma unroll
      for (int ti = 0; ti < 2; ++ti)
        #pragma unroll
        for (int rr = 0; rr < 4; ++rr) {
          float v = acc[ti][t][rr] + bv;
          v = v / (1.f + __expf(-v));
          h1[ti * 16 + lq * 4 + rr][col] = f2bf(v);
        }
    }
  }
  __syncthreads();
  {
    f32x4 acc[2][2];
    #pragma unroll
    for (int ti = 0; ti < 2; ++ti)
      #pragma unroll
      for (int t = 0; t < 2; ++t) acc[ti][t] = (f32x4){0.f, 0.f, 0.f, 0.f};
    #pragma unroll
    for (int k0 = 0; k0 < 256; k0 += 32) {
      bf16x8 a0 = *(const bf16x8*)&h1[lr][k0 + lq * 8];
      bf16x8 a1 = *(const bf16x8*)&h1[16 + lr][k0 + lq * 8];
      #pragma unroll
      for (int t = 0; t < 2; ++t) {
        bf16x8 w = *(const bf16x8*)(W2t + (size_t)(wid * 32 + t * 16 + lr) * 256 + k0 + lq * 8);
        acc[0][t] = __builtin_amdgcn_mfma_f32_16x16x32_bf16(a0, w, acc[0][t], 0, 0, 0);
        acc[1][t] = __builtin_amdgcn_mfma_f32_16x16x32_bf16(a1, w, acc[1][t], 0, 0, 0);
      }
    }
    #pragma unroll
    for (int t = 0; t < 2; ++t) {
      int col = wid * 32 + t * 16 + lr;
      float bv = b2[col];
      #pragma unroll
      for (int ti = 0; ti < 2; ++ti)
        #pragma unroll
        for (int rr = 0; rr < 4; ++rr) {
          float v = acc[ti][t][rr] + bv;
          v = v / (1.f + __expf(-v));
          h2[ti * 16 + lq * 4 + rr][col] = f2bf(v);
        }
    }
  }
  __syncthreads();
  if (wid < 2) {
    const int rbase = wid * 16;
    f32x4 acc = (f32x4){0.f, 0.f, 0.f, 0.f};
    const short* wp = W3t + (size_t)((lr < 4) ? lr : 0) * 256;
    #pragma unroll
    for (int k0 = 0; k0 < 256; k0 += 32) {
      bf16x8 a = *(const bf16x8*)&h2[rbase + lr][k0 + lq * 8];
      bf16x8 w = *(const bf16x8*)(wp + k0 + lq * 8);
      acc = __builtin_amdgcn_mfma_f32_16x16x32_bf16(a, w, acc, 0, 0, 0);
    }
    if (lr < 4) {
      float bv = b3[lr];
      #pragma unroll
      for (int rr = 0; rr < 4; ++rr) {
        int g = m0 + rbase + lq * 4 + rr;
        float pre = acc[rr] + bv;
        float x = fminf(fmaxf(refc[(size_t)g * 4 + lr], 1e-5f), 1.f - 1e-5f);
        float is = logf(x) - log1pf(-x);
        refinit[(size_t)g * 4 + lr] = 1.f / (1.f + __expf(-(pre + is)));
      }
    }
  }
}

// ---------------------------------------------------------------------------
// Fused gateway GEMM + sigmoid + gated-add + LN. 32 rows, 2 row-tiles/wave.
// ---------------------------------------------------------------------------
__launch_bounds__(512)
__global__ void gate_ln(const short* __restrict__ Abf, const short* __restrict__ tbf,
                        const short* __restrict__ Wt, const float* __restrict__ bias,
                        const float* __restrict__ t2,
                        const float* __restrict__ gamma, const float* __restrict__ beta,
                        float* __restrict__ output, short* __restrict__ outbf) {
  __shared__ float sg[32][520];
  const int m0 = blockIdx.x * 32;
  const int tid = threadIdx.x, wid = tid >> 6, lane = tid & 63;
  const int lr = lane & 15, lq = lane >> 4;
  f32x4 acc[2][4];
  #pragma unroll
  for (int ti = 0; ti < 2; ++ti)
    #pragma unroll
    for (int t = 0; t < 4; ++t) acc[ti][t] = (f32x4){0.f, 0.f, 0.f, 0.f};
  #pragma unroll 4
  for (int k0 = 0; k0 < 512; k0 += 32) {
    const short* src = (k0 < 256) ? Abf : tbf;
    int ko = (k0 < 256) ? k0 : k0 - 256;
    bf16x8 a0 = *(const bf16x8*)(src + (size_t)(m0 + lr) * 256 + ko + lq * 8);
    bf16x8 a1 = *(const bf16x8*)(src + (size_t)(m0 + 16 + lr) * 256 + ko + lq * 8);
    #pragma unroll
    for (int t = 0; t < 4; ++t) {
      bf16x8 w = *(const bf16x8*)(Wt + (size_t)(wid * 64 + t * 16 + lr) * 512 + k0 + lq * 8);
      acc[0][t] = __builtin_amdgcn_mfma_f32_16x16x32_bf16(a0, w, acc[0][t], 0, 0, 0);
      acc[1][t] = __builtin_amdgcn_mfma_f32_16x16x32_bf16(a1, w, acc[1][t], 0, 0, 0);
    }
  }
  #pragma unroll
  for (int t = 0; t < 4; ++t) {
    int col = wid * 64 + t * 16 + lr;
    float bv = bias[col];
    #pragma unroll
    for (int ti = 0; ti < 2; ++ti)
      #pragma unroll
      for (int rr = 0; rr < 4; ++rr) {
        int rl = ti * 16 + lq * 4 + rr;
        sg[rl][col] = 1.f / (1.f + __expf(-(acc[ti][t][rr] + bv)));
      }
  }
  __syncthreads();
  // LN phase: 8 waves x 4 rows; lane covers 4 cols.
  #pragma unroll
  for (int it = 0; it < 4; ++it) {
    int rl = wid + it * 8;
    int rowg = m0 + rl;
    int c = lane * 4;
    float4 o4 = *(const float4*)(output + (size_t)rowg * 256 + c);
    float4 t4 = *(const float4*)(t2 + (size_t)rowg * 256 + c);
    float4 g1 = *(const float4*)&sg[rl][c];
    float4 g2 = *(const float4*)&sg[rl][256 + c];
    float x0 = g1.x * o4.x + g2.x * t4.x;
    float x1 = g1.y * o4.y + g2.y * t4.y;
    float x2 = g1.z * o4.z + g2.z * t4.z;
    float x3 = g1.w * o4.w + g2.w * t4.w;
    float s = x0 + x1 + x2 + x3;
    float q = x0 * x0 + x1 * x1 + x2 * x2 + x3 * x3;
    #pragma unroll
    for (int o = 32; o; o >>= 1) { s += __shfl_xor(s, o); q += __shfl_xor(q, o); }
    float mu = s * (1.f / 256.f);
    float var = q * (1.f / 256.f) - mu * mu;
    float rs = rsqrtf(var + 1e-5f);
    float4 ga = *(const float4*)(gamma + c);
    float4 be = *(const float4*)(beta + c);
    float v0 = (x0 - mu) * rs * ga.x + be.x;
    float v1 = (x1 - mu) * rs * ga.y + be.y;
    float v2 = (x2 - mu) * rs * ga.z + be.z;
    float v3 = (x3 - mu) * rs * ga.w + be.w;
    float4 vo; vo.x = v0; vo.y = v1; vo.z = v2; vo.w = v3;
    *(float4*)(output + (size_t)rowg * 256 + c) = vo;
    short4 vs; vs.x = f2bf(v0); vs.y = f2bf(v1); vs.z = f2bf(v2); vs.w = f2bf(v3);
    *(short4*)(outbf + (size_t)rowg * 256 + c) = vs;
  }
}

// ---------------------------------------------------------------------------
// MFMA self-attention. Block per (b,h,half).
// ---------------------------------------------------------------------------
__launch_bounds__(256)
__global__ void attn3_kernel(const short* __restrict__ qkv, short* __restrict__ O) {
  __shared__ short Kb[304][40];
  __shared__ short Vt[32][328];
  __shared__ short Pw[4][16][328];
  const int half = blockIdx.x & 1, bh = blockIdx.x >> 1;
  const int h = bh & 7, b = bh >> 3;
  const int tid = threadIdx.x;
  const short* QKVb = qkv + (size_t)b * LQ_ * 768;
  for (int idx = tid; idx < 304 * 4; idx += 256) {
    int row = idx >> 2, seg = (idx & 3) * 8;
    bf16x8 v = (row < 300) ? *(const bf16x8*)(QKVb + (size_t)row * 768 + 256 + h * 32 + seg)
                           : (bf16x8){0,0,0,0,0,0,0,0};
    *(bf16x8*)&Kb[row][seg] = v;
  }
  for (int idx = tid; idx < 300 * 4; idx += 256) {
    int row = idx >> 2, seg = (idx & 3) * 8;
    bf16x8 v = *(const bf16x8*)(QKVb + (size_t)row * 768 + 512 + h * 32 + seg);
    #pragma unroll
    for (int j = 0; j < 8; ++j) Vt[seg + j][row] = v[j];
  }
  for (int idx = tid; idx < 32 * 20; idx += 256) Vt[idx / 20][300 + idx % 20] = 0;
  for (int idx = tid; idx < 4 * 16 * 16; idx += 256)
    Pw[idx >> 8][(idx >> 4) & 15][304 + (idx & 15)] = 0;
  __syncthreads();

  const int wid = tid >> 6, lane = tid & 63;
  const int lr = lane & 15, lq = lane >> 4;
  short (*Pl)[328] = Pw[wid];
  const float scale = 0.17677669529663687f;

  for (int qt = wid; qt < 10; qt += 4) {
    const int q0 = half * 150 + qt * 16;
    int qrow = q0 + lr; if (qrow > 299) qrow = 299;
    bf16x8 af_q = *(const bf16x8*)(QKVb + (size_t)qrow * 768 + h * 32 + lq * 8);
    f32x4 s[19];
    #pragma unroll
    for (int t = 0; t < 19; ++t) {
      bf16x8 bk = *(const bf16x8*)&Kb[t * 16 + lr][lq * 8];
      s[t] = __builtin_amdgcn_mfma_f32_16x16x32_bf16(af_q, bk, (f32x4){0.f,0.f,0.f,0.f}, 0, 0, 0);
    }
    #pragma unroll
    for (int t = 0; t < 19; ++t)
      #pragma unroll
      for (int r = 0; r < 4; ++r) s[t][r] *= scale;
    if (lr >= 12) { s[18][0] = s[18][1] = s[18][2] = s[18][3] = -1e30f; }
    float l[4];
    #pragma unroll
    for (int r = 0; r < 4; ++r) {
      float mm = -1e30f;
      #pragma unroll
      for (int t = 0; t < 19; ++t) mm = fmaxf(mm, s[t][r]);
      #pragma unroll
      for (int x = 1; x < 16; x <<= 1) mm = fmaxf(mm, __shfl_xor(mm, x));
      float ll = 0.f;
      #pragma unroll
      for (int t = 0; t < 19; ++t) { float p = __expf(s[t][r] - mm); s[t][r] = p; ll += p; }
      #pragma unroll
      for (int x = 1; x < 16; x <<= 1) ll += __shfl_xor(ll, x);
      l[r] = ll;
    }
    #pragma unroll
    for (int t = 0; t < 19; ++t)
      #pragma unroll
      for (int r = 0; r < 4; ++r) Pl[lq * 4 + r][t * 16 + lr] = f2bf(s[t][r]);
    f32x4 o0 = (f32x4){0.f,0.f,0.f,0.f}, o1 = (f32x4){0.f,0.f,0.f,0.f};
    #pragma unroll
    for (int c = 0; c < 10; ++c) {
      bf16x8 ap = *(const bf16x8*)&Pl[lr][c * 32 + lq * 8];
      bf16x8 v0 = *(const bf16x8*)&Vt[lr][c * 32 + lq * 8];
      bf16x8 v1 = *(const bf16x8*)&Vt[16 + lr][c * 32 + lq * 8];
      o0 = __builtin_amdgcn_mfma_f32_16x16x32_bf16(ap, v0, o0, 0, 0, 0);
      o1 = __builtin_amdgcn_mfma_f32_16x16x32_bf16(ap, v1, o1, 0, 0, 0);
    }
    #pragma unroll
    for (int r = 0; r < 4; ++r) {
      int q = q0 + lq * 4 + r;
      if (q >= 300) continue;
      float inv = 1.f / l[r];
      size_t ob = (size_t)(b * LQ_ + q) * 256 + h * 32;
      O[ob + lr]      = f2bf(o0[r] * inv);
      O[ob + 16 + lr] = f2bf(o1[r] * inv);
    }
  }
}

// ---------------------------------------------------------------------------
// Deformable sampling, 2 rows/block (512 threads), branch-free taps.
// ---------------------------------------------------------------------------
template<int BF16MEM>
__launch_bounds__(512)
__global__ void deform_kernel(const void* __restrict__ memv, const float* __restrict__ offaw,
                              const float* __restrict__ refp,
                              float* __restrict__ t2, short* __restrict__ t2bf) {
  const int bi = blockIdx.x;
  const int tid = threadIdx.x;
  const int sub = tid >> 8;
  const int row = (bi & 7) * 600 + (bi >> 3) * 2 + sub;   // XCD locality swizzle
  const int b = row / LQ_;
  const int it = tid & 255;
  const int h = it >> 5, c = it & 31;
  const float rx = refp[row * 4 + 0], ry = refp[row * 4 + 1];
  const float rw = refp[row * 4 + 2], rh = refp[row * 4 + 3];
  const float* awp = offaw + (size_t)row * 288 + 192 + h * SUMP_;
  float wv[SUMP_];
  float wmax = -1e30f;
  #pragma unroll
  for (int p = 0; p < SUMP_; ++p) { wv[p] = awp[p]; wmax = fmaxf(wmax, wv[p]); }
  float wsum = 0.f;
  #pragma unroll
  for (int p = 0; p < SUMP_; ++p) { wv[p] = __expf(wv[p] - wmax); wsum += wv[p]; }
  const float winv = 1.f / wsum;
  const float* op = offaw + (size_t)row * 288 + h * (SUMP_ * 2);
  const short* mb16 = BF16MEM ? ((const short*)memv + ((size_t)(b * 8 + h) * STOT_) * 32 + c) : nullptr;
  const float* mb32 = BF16MEM ? nullptr : ((const float*)memv + (size_t)b * STOT_ * 256 + h * 32 + c);
  float acc = 0.f;
  #pragma unroll
  for (int p = 0; p < SUMP_; ++p) {
    const int lvl = p >> 2;
    const int Wl = (lvl == 0) ? 80 : ((lvl == 1) ? 40 : 20);
    const int s0 = (lvl == 0) ? 0 : ((lvl == 1) ? 6400 : 8000);
    float lx = rx + op[2 * p]     * 0.125f * rw;
    float ly = ry + op[2 * p + 1] * 0.125f * rh;
    float x = lx * Wl - 0.5f, y = ly * Wl - 0.5f;
    float xf = floorf(x), yf = floorf(y);
    int x0 = (int)xf, y0 = (int)yf;
    float wx = x - xf, wy = y - yf;
    int x0c = min(max(x0, 0), Wl - 1), x1c = min(max(x0 + 1, 0), Wl - 1);
    int y0c = min(max(y0, 0), Wl - 1), y1c = min(max(y0 + 1, 0), Wl - 1);
    float wx0 = (x0 >= 0 && x0 < Wl) ? (1.f - wx) : 0.f;
    float wx1 = (x0 + 1 >= 0 && x0 + 1 < Wl) ? wx : 0.f;
    float wy0 = (y0 >= 0 && y0 < Wl) ? (1.f - wy) : 0.f;
    float wy1 = (y0 + 1 >= 0 && y0 + 1 < Wl) ? wy : 0.f;
    float v;
    if (BF16MEM) {
      const short* mb = mb16 + (size_t)s0 * 32;
      v = wx0 * wy0 * bf2f(mb[(size_t)(y0c * Wl + x0c) * 32])
        + wx1 * wy0 * bf2f(mb[(size_t)(y0c * Wl + x1c) * 32])
        + wx0 * wy1 * bf2f(mb[(size_t)(y1c * Wl + x0c) * 32])
        + wx1 * wy1 * bf2f(mb[(size_t)(y1c * Wl + x1c) * 32]);
    } else {
      const float* mb = mb32 + (size_t)s0 * 256;
      v = wx0 * wy0 * mb[(size_t)(y0c * Wl + x0c) * 256]
        + wx1 * wy0 * mb[(size_t)(y0c * Wl + x1c) * 256]
        + wx0 * wy1 * mb[(size_t)(y1c * Wl + x0c) * 256]
        + wx1 * wy1 * mb[(size_t)(y1c * Wl + x1c) * 256];
    }
    acc += wv[p] * winv * v;
  }
  size_t off = (size_t)row * D_ + h * HD_ + c;
  t2[off] = acc;
  t2bf[off] = f2bf(acc);
}

// ---------------------------------------------------------------------------
// host orchestration
// ---------------------------------------------------------------------------
static inline dim3 egrid(int n) { return dim3((n + 255) / 256); }

extern "C" void kernel_launch(void* const* d_in, const int* in_sizes, int n_in,
                              void* d_out, int out_size, void* d_ws, size_t ws_size,
                              hipStream_t stream) {
  const float* target     = (const float*)d_in[0];
  const float* ref_unact  = (const float*)d_in[1];
  const float* memory     = (const float*)d_in[2];
  const float* sa_qw = (const float*)d_in[3];  const float* sa_qb = (const float*)d_in[4];
  const float* sa_kw = (const float*)d_in[5];  const float* sa_kb = (const float*)d_in[6];
  const float* sa_vw = (const float*)d_in[7];  const float* sa_vb = (const float*)d_in[8];
  const float* sa_ow = (const float*)d_in[9];  const float* sa_ob = (const float*)d_in[10];
  const float* n1_g  = (const float*)d_in[11]; const float* n1_b  = (const float*)d_in[12];
  const float* off_w = (const float*)d_in[13]; const float* off_b = (const float*)d_in[14];
  const float* aw_w  = (const float*)d_in[15]; const float* aw_b  = (const float*)d_in[16];
  const float* gate_w= (const float*)d_in[17]; const float* gate_b= (const float*)d_in[18];
  const float* gn_g  = (const float*)d_in[19]; const float* gn_b  = (const float*)d_in[20];
  const float* ff1_w = (const float*)d_in[21]; const float* ff1_b = (const float*)d_in[22];
  const float* ff2_w = (const float*)d_in[23]; const float* ff2_b = (const float*)d_in[24];
  const float* n3_g  = (const float*)d_in[25]; const float* n3_b  = (const float*)d_in[26];
  const float* bb_w1 = (const float*)d_in[27]; const float* bb_b1 = (const float*)d_in[28];
  const float* bb_w2 = (const float*)d_in[29]; const float* bb_b2 = (const float*)d_in[30];
  const float* bb_w3 = (const float*)d_in[31]; const float* bb_b3 = (const float*)d_in[32];
  const float* sc_w  = (const float*)d_in[33]; const float* sc_b  = (const float*)d_in[34];
  const float* lqe_w1= (const float*)d_in[35]; const float* lqe_b1= (const float*)d_in[36];
  const float* lqe_w2= (const float*)d_in[37]; const float* lqe_b2= (const float*)d_in[38];
  const float* qp_w1 = (const float*)d_in[39]; const float* qp_b1 = (const float*)d_in[40];
  const float* qp_w2 = (const float*)d_in[41]; const float* qp_b2 = (const float*)d_in[42];
  const float* pb_w1 = (const float*)d_in[43]; const float* pb_b1 = (const float*)d_in[44];
  const float* pb_w2 = (const float*)d_in[45]; const float* pb_b2 = (const float*)d_in[46];
  const float* pb_w3 = (const float*)d_in[47]; const float* pb_b3 = (const float*)d_in[48];
  float* out = (float*)d_out;

  // ---- workspace: fp32 region ----
  float* ws = (float*)d_ws;
  size_t woff = 0;
  auto alloc = [&](size_t n) { float* p = ws + woff; woff += n; return p; };
  float* output   = alloc((size_t)R_ * D_);
  float* out_prev = alloc((size_t)R_ * D_);
  float* qp       = alloc((size_t)R_ * D_);
  float* t2       = alloc((size_t)R_ * D_);
  float* offawf   = alloc((size_t)R_ * 288);  // also scores
  float* U        = alloc((size_t)R_ * 512);  // qkv (bf16)
  float* corners0 = alloc((size_t)R_ * 4 * NBIN_);
  float* corners1 = alloc((size_t)R_ * 4 * NBIN_);
  float* refA     = alloc((size_t)R_ * 4);
  float* refB     = alloc((size_t)R_ * 4);
  float* ref_init = alloc((size_t)R_ * 4);
  float* qkvb     = alloc((size_t)NLAYERS_ * 768);
  float* offawb   = alloc((size_t)NLAYERS_ * 288);

  // ---- workspace: bf16 region ----
  short* sws = (short*)(ws + woff);
  size_t soff = 0;
  auto salloc = [&](size_t n) { short* p = sws + soff; soff += n; return p; };
  short* outbf = salloc((size_t)R_ * D_);
  short* oqbf  = salloc((size_t)R_ * D_);
  short* tbf   = salloc((size_t)R_ * D_);
  short* qp2t  = salloc((size_t)256 * 512);
  short* sqkvt = salloc((size_t)NLAYERS_ * 768 * 256);
  short* sowt  = salloc((size_t)NLAYERS_ * 256 * 256);
  short* soffawt = salloc((size_t)NLAYERS_ * 288 * 256);
  short* gatet = salloc((size_t)NLAYERS_ * 512 * 512);
  short* ff1t  = salloc((size_t)NLAYERS_ * 1024 * 256);
  short* ff2t  = salloc((size_t)NLAYERS_ * 256 * 1024);
  short* bb1t  = salloc((size_t)NLAYERS_ * 256 * 256);
  short* bb2t  = salloc((size_t)NLAYERS_ * 256 * 256);
  short* bb3t  = salloc((size_t)NLAYERS_ * 132 * 256);
  short* pb1t  = salloc((size_t)256 * 256);
  short* pb2t  = salloc((size_t)256 * 256);
  short* pb3t  = salloc((size_t)4 * 256);
  short* sct   = salloc((size_t)80 * 256);
  size_t base_bytes = woff * sizeof(float) + soff * sizeof(short);
  if (ws_size < base_bytes) return;
  const size_t memn = (size_t)B_ * STOT_ * 256;
  bool bf16mem = (ws_size >= base_bytes + memn * sizeof(short));
  short* membf = sws + soff;

  short* qkv    = (short*)U;
  float* scores = offawf;

  float* c_prev = corners0; float* c_cur = corners1;
  float* ref_cur = refA;    float* ref_nxt = refB;

  // ---- weight prep: single dispatch ----
  WJobs P; int nb = 0; int nj = 0;
  auto addj = [&](const float* s, short* d2, int K, int N, int L, int ostr) {
    P.j[nj].src = s; P.j[nj].dst = d2; P.j[nj].K = K; P.j[nj].N = N;
    P.j[nj].tk = (K + 31) / 32; P.j[nj].tn = (N + 31) / 32;
    P.j[nj].L = L; P.j[nj].ostride = ostr; P.j[nj].blk0 = nb; P.j[nj].pad = 0;
    nb += P.j[nj].tk * P.j[nj].tn * L; ++nj;
  };
  addj(qp_w2, qp2t, 512, 256, 1, 512 * 256);
  addj(sa_qw, sqkvt,               256, 256, NLAYERS_, 768 * 256);
  addj(sa_kw, sqkvt + 256 * 256,   256, 256, NLAYERS_, 768 * 256);
  addj(sa_vw, sqkvt + 512 * 256,   256, 256, NLAYERS_, 768 * 256);
  addj(sa_ow, sowt, 256, 256, NLAYERS_, 256 * 256);
  addj(off_w, soffawt,             256, 192, NLAYERS_, 288 * 256);
  addj(aw_w,  soffawt + 192 * 256, 256,  96, NLAYERS_, 288 * 256);
  addj(gate_w, gatet, 512, 512, NLAYERS_, 512 * 512);
  addj(ff1_w, ff1t, 256, 1024, NLAYERS_, 1024 * 256);
  addj(ff2_w, ff2t, 1024, 256, NLAYERS_, 256 * 1024);
  addj(bb_w1, bb1t, 256, 256, NLAYERS_, 256 * 256);
  addj(bb_w2, bb2t, 256, 256, NLAYERS_, 256 * 256);
  addj(bb_w3, bb3t, 256, 132, NLAYERS_, 132 * 256);
  addj(pb_w1, pb1t, 256, 256, 1, 256 * 256);
  addj(pb_w2, pb2t, 256, 256, 1, 256 * 256);
  addj(pb_w3, pb3t, 256, 4, 1, 4 * 256);
  addj(sc_w + (size_t)5 * D_ * NC_, sct, 256, 80, 1, 80 * 256);
  P.njobs = nj;
  wconv_all<<<dim3(nb), 256, 0, stream>>>(P);
  if (bf16mem)
    memconv_kernel<<<dim3(B_ * STOT_ / 4), 256, 0, stream>>>(memory, membf);

  // ---- init (single dispatch) ----
  misc_init<<<egrid(R_ * 64), 256, 0, stream>>>(target, ref_unact,
      sa_qb, sa_kb, sa_vb, off_b, aw_b,
      output, outbf, out_prev, c_prev, ref_cur, qkvb, offawb);

  for (int i = 0; i < NLAYERS_; ++i) {
    // qp MLP + qkv GEMM fused
    qp_qkv<<<dim3(150), 512, 0, stream>>>(ref_cur, qp_w1, qp_b1, qp2t, qp_b2,
                                          output, outbf,
                                          sqkvt + (size_t)i * 768 * 256,
                                          qkvb + (size_t)i * 768, qp, qkv);
    attn3_kernel<<<dim3(B_ * NH_ * 2), 256, 0, stream>>>(qkv, tbf);
    // sow GEMM + ln0 + offset/attn-weight GEMM fused
    sow_ln_off<<<dim3(150), 512, 0, stream>>>(
        tbf, sowt + (size_t)i * 65536, sa_ob + (size_t)i * D_, output,
        n1_g + (size_t)i * D_, n1_b + (size_t)i * D_, qp,
        soffawt + (size_t)i * 288 * 256, offawb + (size_t)i * 288,
        output, outbf, offawf);

    // ---- deformable cross attention ----
    if (bf16mem)
      deform_kernel<1><<<dim3(R_ / 2), 512, 0, stream>>>(membf, offawf, ref_cur, t2, tbf);
    else
      deform_kernel<0><<<dim3(R_ / 2), 512, 0, stream>>>(memory, offawf, ref_cur, t2, tbf);

    // ---- gateway ----
    gate_ln<<<dim3(150), 512, 0, stream>>>(outbf, tbf, gatet + (size_t)i * 262144,
                                           gate_b + (size_t)i * 512, t2,
                                           gn_g + (size_t)i * D_, gn_b + (size_t)i * D_,
                                           output, outbf);

    // ---- FFN (+ scores at layer 5) ----
    if (i < NLAYERS_ - 1)
      ffn_ln<0><<<dim3(150), 512, 0, stream>>>(outbf, ff1t + (size_t)i * 262144,
          ff1_b + (size_t)i * FF_, ff2t + (size_t)i * 262144, ff2_b + (size_t)i * D_,
          output, n3_g + (size_t)i * D_, n3_b + (size_t)i * D_,
          out_prev, output, outbf, oqbf, nullptr, nullptr, nullptr);
    else
      ffn_ln<1><<<dim3(150), 512, 0, stream>>>(outbf, ff1t + (size_t)i * 262144,
          ff1_b + (size_t)i * FF_, ff2t + (size_t)i * 262144, ff2_b + (size_t)i * D_,
          output, n3_g + (size_t)i * D_, n3_b + (size_t)i * D_,
          out_prev, output, outbf, oqbf, sct, sc_b + (size_t)5 * NC_, scores);

    // ---- FDR box refinement (+ LQE at layer 5) ----
    if (i == 0)
      pb_fused<<<dim3(150), 512, 0, stream>>>(outbf, pb1t, pb_b1, pb2t, pb_b2,
                                              pb3t, pb_b3, ref_cur, ref_init);
    if (i < NLAYERS_ - 1) {
      fdr_kernel<0><<<dim3(150), 512, 0, stream>>>(oqbf,
          bb1t + (size_t)i * 65536, bb_b1 + (size_t)i * D_,
          bb2t + (size_t)i * 65536, bb_b2 + (size_t)i * D_,
          bb3t + (size_t)i * 33792, bb_b3 + (size_t)i * 4 * NBIN_,
          c_prev, ref_init, c_cur, ref_nxt,
          nullptr, nullptr, nullptr, nullptr, nullptr, nullptr);
      std::swap(c_prev, c_cur);
      std::swap(ref_cur, ref_nxt);
    } else {
      fdr_kernel<1><<<dim3(150), 512, 0, stream>>>(oqbf,
          bb1t + (size_t)i * 65536, bb_b1 + (size_t)i * D_,
          bb2t + (size_t)i * 65536, bb_b2 + (size_t)i * D_,
          bb3t + (size_t)i * 33792, bb_b3 + (size_t)i * 4 * NBIN_,
          c_prev, ref_init, c_cur, ref_nxt,
          scores, lqe_w1 + (size_t)5 * 20 * 64, lqe_b1 + (size_t)5 * 64,
          lqe_w2 + (size_t)5 * 64, lqe_b2 + (size_t)5, out);
    }
  }
}